// Round 7
// baseline (997.020 us; speedup 1.0000x reference)
//
#include <hip/hip_runtime.h>
#include <math.h>

#define Nn 16384
#define Fd 64
#define Hd 128
#define Kk 32

typedef short bfrag __attribute__((ext_vector_type(8)));    // 8 bf16 = 4 VGPR
typedef float f32x16 __attribute__((ext_vector_type(16)));  // MFMA 32x32 acc

#define FMA16(acc, qv, pv) \
  acc[0][0]=fmaf(qv.x,pv.x,acc[0][0]); acc[0][1]=fmaf(qv.x,pv.y,acc[0][1]); \
  acc[0][2]=fmaf(qv.x,pv.z,acc[0][2]); acc[0][3]=fmaf(qv.x,pv.w,acc[0][3]); \
  acc[1][0]=fmaf(qv.y,pv.x,acc[1][0]); acc[1][1]=fmaf(qv.y,pv.y,acc[1][1]); \
  acc[1][2]=fmaf(qv.y,pv.z,acc[1][2]); acc[1][3]=fmaf(qv.y,pv.w,acc[1][3]); \
  acc[2][0]=fmaf(qv.z,pv.x,acc[2][0]); acc[2][1]=fmaf(qv.z,pv.y,acc[2][1]); \
  acc[2][2]=fmaf(qv.z,pv.z,acc[2][2]); acc[2][3]=fmaf(qv.z,pv.w,acc[2][3]); \
  acc[3][0]=fmaf(qv.w,pv.x,acc[3][0]); acc[3][1]=fmaf(qv.w,pv.y,acc[3][1]); \
  acc[3][2]=fmaf(qv.w,pv.z,acc[3][2]); acc[3][3]=fmaf(qv.w,pv.w,acc[3][3]);

// ---------------- hidden0 = x @ W_in + b_in ; sq[i] = sum(x_i^2) ----------------
__global__ __launch_bounds__(256) void k_input(const float* __restrict__ x,
    const float* __restrict__ W, const float* __restrict__ b,
    float* __restrict__ hid, float* __restrict__ sq) {
  const int t = threadIdx.x;
  const int i = (blockIdx.x << 1) + (t >> 7);
  const int h = t & 127;
  const float* xr = x + (size_t)i * Fd;
  float acc = 0.f, s = 0.f;
#pragma unroll 8
  for (int f = 0; f < Fd; ++f) {
    float xv = xr[f];
    acc = fmaf(xv, W[f * Hd + h], acc);
    s = fmaf(xv, xv, s);
  }
  hid[(size_t)i * Hd + h] = acc + b[h];
  if (h == 0) sq[i] = s;
}

// ------------- precompute x as bf16 hi/lo in MFMA-fragment order -------------
__global__ __launch_bounds__(256) void k_prep(const float* __restrict__ x,
    short* __restrict__ xh, short* __restrict__ xl) {
  const int gid = blockIdx.x * 256 + threadIdx.x;
  const int p = gid >> 3, sub = gid & 7;
  const float* src = x + (size_t)p * Fd + sub * 8;
  float4 v0 = *(const float4*)src;
  float4 v1 = *(const float4*)(src + 4);
  float vv[8] = {v0.x, v0.y, v0.z, v0.w, v1.x, v1.y, v1.z, v1.w};
  bfrag hi, lo;
#pragma unroll
  for (int j = 0; j < 8; ++j) {
    unsigned u = __float_as_uint(vv[j]);
    unsigned r = u + 0x7fffu + ((u >> 16) & 1u);
    unsigned short hb = (unsigned short)(r >> 16);
    float hf = __uint_as_float((unsigned)hb << 16);
    float lof = vv[j] - hf;
    unsigned ul = __float_as_uint(lof);
    unsigned rl = ul + 0x7fffu + ((ul >> 16) & 1u);
    hi[j] = (short)hb;
    lo[j] = (short)(rl >> 16);
  }
  const size_t o = (size_t)(p >> 5) * 2048 + (size_t)sub * 256 + (size_t)(p & 31) * 8;
  *(bfrag*)(xh + o) = hi;
  *(bfrag*)(xl + o) = lo;
}

// ---------------- KNN: MFMA distance GEMM + streaming exact top-32 ----------------
// 256 thr (4 waves), 32 queries/block, 128-pt tiles, grid 512 = 2 blocks/CU.
// Owners spread across all 4 waves (8 lanes each) -> INSERT on all 4 SIMDs.
// Double-buffered candidate queue -> ONE barrier per tile.
// topk stride 33 u64 -> bank (2q+2k)%32, conflict-free RESCAN.
// Packed key (f32bits(d2)<<16 | idx): strict total order -> deterministic.
#define QCAP 128
#define QSTR 129
#define TSTR 33
#define KEYMAX 0xFFFFFFFFFFFFFFFFull

__global__ __launch_bounds__(256, 2) void k_knn(const short* __restrict__ xbhi,
    const short* __restrict__ xblo, const float* __restrict__ sq,
    unsigned short* __restrict__ nidx, float* __restrict__ nw) {
  __shared__ __align__(16) unsigned long long qkey[2][32 * QSTR];  // 66 KB
  __shared__ __align__(16) unsigned long long topk[32 * TSTR];     // 8.4 KB
  __shared__ __align__(16) float sqq_s[32];
  __shared__ __align__(16) float thrRow[32];
  __shared__ unsigned qcnt[2][32];

  const int t = threadIdx.x;
  const int w = t >> 6;
  const int lane = t & 63;
  const int h = lane >> 5;
  const int col = lane & 31;
  const int qg0 = blockIdx.x * 32;
  const int selfTileIdx = (int)(blockIdx.x >> 2);  // 32 | 128 aligned

  for (int i = t; i < 32 * TSTR; i += 256) topk[i] = KEYMAX;
  if (t < 32) {
    sqq_s[t] = sq[qg0 + t]; thrRow[t] = -5e29f;
    qcnt[0][t] = 0; qcnt[1][t] = 0;
  }

  // owner lanes: 8 per wave -> INSERT work on every SIMD
  const int ownq = (lane < 8) ? (w * 8 + lane) : -1;
  unsigned long long wk = KEYMAX; int mp = 0; int ocnt = 0;
  const float sqqR = (ownq >= 0) ? sq[qg0 + ownq] : 0.f;

  const char* xh = (const char*)xbhi;
  const char* xl = (const char*)xblo;

  // A fragments (one query group, hi+lo) resident: 32 VGPR
  bfrag ahi[4], alo[4];
  {
    const size_t a0 = (size_t)blockIdx.x * 4096 + (size_t)lane * 16;
#pragma unroll
    for (int s = 0; s < 4; ++s) {
      ahi[s] = *(const bfrag*)(xh + a0 + s * 1024);
      alo[s] = *(const bfrag*)(xl + a0 + s * 1024);
    }
  }
  asm volatile("" :: "v"(ahi[0]), "v"(ahi[1]), "v"(ahi[2]), "v"(ahi[3]),
                     "v"(alo[0]), "v"(alo[1]), "v"(alo[2]), "v"(alo[3]));
  __syncthreads();

#define LOADB(TL, BH, BL, SPD) { \
  const size_t bb_ = (size_t)((TL) * 4 + w) * 4096 + (size_t)lane * 16; \
  _Pragma("unroll") for (int s_ = 0; s_ < 4; ++s_) { \
    BH[s_] = *(const bfrag*)(xh + bb_ + s_ * 1024); \
    BL[s_] = *(const bfrag*)(xl + bb_ + s_ * 1024); } \
  SPD = sq[(TL) * 128 + w * 32 + col]; }

#define PIN(BH, BL) asm volatile("" :: "v"(BH[0]), "v"(BH[1]), "v"(BH[2]), "v"(BH[3]), \
                                       "v"(BL[0]), "v"(BL[1]), "v"(BL[2]), "v"(BL[3]));

#define MFMA12(A0, BH, BL) { \
  _Pragma("unroll") for (int s_ = 0; s_ < 4; ++s_) \
    A0 = __builtin_amdgcn_mfma_f32_32x32x16_bf16(ahi[s_], BH[s_], A0, 0, 0, 0); \
  _Pragma("unroll") for (int s_ = 0; s_ < 4; ++s_) \
    A0 = __builtin_amdgcn_mfma_f32_32x32x16_bf16(ahi[s_], BL[s_], A0, 0, 0, 0); \
  _Pragma("unroll") for (int s_ = 0; s_ < 4; ++s_) \
    A0 = __builtin_amdgcn_mfma_f32_32x32x16_bf16(alo[s_], BH[s_], A0, 0, 0, 0); }

  // worst = max key; 32 independent conflict-free b64 reads + compare chain
#define RESCAN { wk = 0ull; mp = 0; \
  _Pragma("unroll") for (int k_ = 0; k_ < 32; ++k_) { \
    unsigned long long v_ = topk[ownq * TSTR + k_]; \
    if (v_ > wk) { wk = v_; mp = k_; } } }

#define INSERT(FIXEDN, QB) { \
  if (ownq >= 0) { \
    int n_ = ((FIXEDN) >= 0) ? (FIXEDN) : (int)qcnt[QB][ownq]; \
    if (n_ > QCAP) n_ = QCAP; \
    for (int e_ = 0; e_ < n_; ++e_) { \
      unsigned long long k_ = qkey[QB][ownq * QSTR + e_]; \
      if (ocnt < 32) { \
        topk[ownq * TSTR + ocnt] = k_; \
        ocnt++; \
        if (ocnt == 32) { RESCAN } \
      } else if (k_ < wk) { \
        topk[ownq * TSTR + mp] = k_; \
        RESCAN \
      } } \
    if ((FIXEDN) < 0 && n_ > 0) qcnt[QB][ownq] = 0; \
    if (ocnt == 32) { \
      const float mvd_ = __uint_as_float((unsigned)(wk >> 16)); \
      thrRow[ownq] = 0.5f * (sqqR - mvd_); \
    } } }

  // candidate iff d2 <= tau  <=>  acc >= 0.5*(sqq - tau) + 0.5*sqp
#define PUSHQ(ACC, TL, SPv, QB) { \
  const float sph_ = 0.5f * (SPv); \
  _Pragma("unroll") for (int m_ = 0; m_ < 4; ++m_) { \
    const float4 th_ = *(const float4*)&thrRow[m_ * 8 + h * 4]; \
    _Pragma("unroll") for (int b_ = 0; b_ < 4; ++b_) { \
      const float av_ = ACC[m_ * 4 + b_]; \
      const float tb_ = (b_ == 0) ? th_.x : (b_ == 1) ? th_.y : (b_ == 2) ? th_.z : th_.w; \
      if (av_ >= tb_ + sph_) { \
        const int qq_ = b_ + 8 * m_ + 4 * h; \
        const int p_ = (TL) * 128 + w * 32 + col; \
        if (!(selfT_ && p_ == qg0 + qq_)) { \
          const float d2_ = fmaxf(sqq_s[qq_] + (SPv)-2.0f * av_, 0.0f); \
          const unsigned sl_ = atomicAdd(&qcnt[QB][qq_], 1u); \
          qkey[QB][qq_ * QSTR + sl_] = \
            ((unsigned long long)__float_as_uint(d2_) << 16) | (unsigned)p_; \
        } } } } }

  // tile 0, waves 0-2: slot = point index (0..95), unique, no atomics
#define PUSH0(ACC, SPv) { \
  _Pragma("unroll") for (int m_ = 0; m_ < 4; ++m_) { \
    _Pragma("unroll") for (int b_ = 0; b_ < 4; ++b_) { \
      const float av_ = ACC[m_ * 4 + b_]; \
      const int qq_ = b_ + 8 * m_ + 4 * h; \
      const int p_ = w * 32 + col; \
      float d2_ = fmaxf(sqq_s[qq_] + (SPv)-2.0f * av_, 0.0f); \
      if (selfT_ && p_ == qg0 + qq_) d2_ = 1e30f; \
      qkey[0][qq_ * QSTR + p_] = \
        ((unsigned long long)__float_as_uint(d2_) << 16) | (unsigned)p_; } } }

  // One barrier per tile: [loads(T+1) || MFMA(T)] -> barrier ->
  //   PUSHQ(T -> buf[T&1]) -> INSERT(buf[(T-1)&1])   (drain overlaps pushes)
#define STEP(TL, BH, BL, SPC, NBH, NBL, NSPC) { \
  const int tl_ = (TL); \
  if (tl_ + 1 < 128) LOADB(tl_ + 1, NBH, NBL, NSPC) \
  f32x16 a0_; \
  _Pragma("unroll") for (int i_ = 0; i_ < 16; ++i_) a0_[i_] = 0.f; \
  MFMA12(a0_, BH, BL) \
  PIN(NBH, NBL) \
  __syncthreads(); \
  const bool selfT_ = (tl_ == selfTileIdx); \
  PUSHQ(a0_, tl_, SPC, (tl_) & 1) \
  INSERT(-1, (tl_ - 1) & 1) }

  bfrag bhA[4], blA[4], bhB[4], blB[4];
  float spA = 0.f, spB = 0.f;

  // ---- tile 0 bootstrap (3 sub-rounds, its own barriers) ----
  LOADB(0, bhA, blA, spA)
  PIN(bhA, blA)
  {
    f32x16 a0_;
#pragma unroll
    for (int i_ = 0; i_ < 16; ++i_) a0_[i_] = 0.f;
    MFMA12(a0_, bhA, blA)
    LOADB(1, bhB, blB, spB)
    PIN(bhB, blB)
    const bool selfT_ = (0 == selfTileIdx);
    if (w < 3) PUSH0(a0_, spA)
    __syncthreads();
    INSERT(96, 0)
    __syncthreads();
    if (w == 3) PUSHQ(a0_, 0, spA, 0)   // tile-0 pushes -> buf0
  }

  // ---- tiles 1..127 (B-register and queue-buffer ping-pong) ----
  for (int tp = 1; tp < 127; tp += 2) {
    STEP(tp, bhB, blB, spB, bhA, blA, spA)
    STEP(tp + 1, bhA, blA, spA, bhB, blB, spB)
  }
  STEP(127, bhB, blB, spB, bhA, blA, spA)
  __syncthreads();
  INSERT(-1, 1)      // drain tile-127 pushes (buf 127&1 = 1)
  __syncthreads();

  // finalize: d=sqrt(d2), softmax(-2d) over the 32 slots (order-invariant)
  {
    const int qq = t >> 3, sl = t & 7;
    float d[4]; int id[4];
    float mn = 1e30f;
#pragma unroll
    for (int u = 0; u < 4; ++u) {
      const unsigned long long k2 = topk[qq * TSTR + sl * 4 + u];
      d[u] = sqrtf(__uint_as_float((unsigned)(k2 >> 16)));
      id[u] = (int)(k2 & 0xFFFFull);
      mn = fminf(mn, d[u]);
    }
#pragma unroll
    for (int m = 1; m < 8; m <<= 1) mn = fminf(mn, __shfl_xor(mn, m));
    float e[4], s2 = 0.f;
#pragma unroll
    for (int u = 0; u < 4; ++u) { e[u] = __expf((mn - d[u]) * 2.0f); s2 += e[u]; }
#pragma unroll
    for (int m = 1; m < 8; m <<= 1) s2 += __shfl_xor(s2, m);
    const float inv = 1.0f / s2;
#pragma unroll
    for (int u = 0; u < 4; ++u) {
      const int o = (qg0 + qq) * Kk + sl * 4 + u;
      nw[o] = e[u] * inv;
      nidx[o] = (unsigned short)id[u];
    }
  }
#undef LOADB
#undef PIN
#undef MFMA12
#undef RESCAN
#undef INSERT
#undef PUSHQ
#undef PUSH0
#undef STEP
}

// ---------------- one message-pass step, fused: gather+MLP+LN ----------------
#define RB 32
#define US 36

__global__ __launch_bounds__(256) void k_step(const float* __restrict__ x,
    const float* __restrict__ hin, const unsigned short* __restrict__ nidx,
    const float* __restrict__ nw, const float* __restrict__ Wm1,
    const float* __restrict__ bm1, const float* __restrict__ Wm2,
    const float* __restrict__ bm2, const float* __restrict__ g,
    const float* __restrict__ be, float* __restrict__ hout) {
  __shared__ float updT[2 * Hd + Fd][US];  // upd_in transposed: 320 x 36 (46 KB)
  __shared__ float t1T[Hd][US];            // silu(GEMM1) transposed (18 KB)
  const int t = threadIdx.x;
  const int r0 = blockIdx.x * RB;

  { // stage: hidden | agg (gather) | x, all transposed
    const int r = t >> 3, s = t & 7;
    const int i = r0 + r;
    const float* hr = hin + (size_t)i * Hd + (s << 4);
#pragma unroll
    for (int u = 0; u < 4; ++u) {
      float4 v = *(const float4*)(hr + (u << 2));
      const int c = (s << 4) + (u << 2);
      updT[c + 0][r] = v.x; updT[c + 1][r] = v.y;
      updT[c + 2][r] = v.z; updT[c + 3][r] = v.w;
    }
    float a[16];
#pragma unroll
    for (int u = 0; u < 16; ++u) a[u] = 0.f;
    const unsigned short* ir = nidx + i * Kk;
    const float* wr = nw + i * Kk;
    for (int k = 0; k < Kk; ++k) {
      const float wk = wr[k];
      const float* hv = hin + (size_t)ir[k] * Hd + (s << 4);
#pragma unroll
      for (int u = 0; u < 4; ++u) {
        float4 v = *(const float4*)(hv + (u << 2));
        a[(u << 2) + 0] = fmaf(wk, v.x, a[(u << 2) + 0]);
        a[(u << 2) + 1] = fmaf(wk, v.y, a[(u << 2) + 1]);
        a[(u << 2) + 2] = fmaf(wk, v.z, a[(u << 2) + 2]);
        a[(u << 2) + 3] = fmaf(wk, v.w, a[(u << 2) + 3]);
      }
    }
#pragma unroll
    for (int u = 0; u < 16; ++u) updT[Hd + (s << 4) + u][r] = a[u];
    const float* xr = x + (size_t)i * Fd + (s << 3);
    float4 x0 = *(const float4*)(xr);
    float4 x1 = *(const float4*)(xr + 4);
    const int c = 2 * Hd + (s << 3);
    updT[c + 0][r] = x0.x; updT[c + 1][r] = x0.y;
    updT[c + 2][r] = x0.z; updT[c + 3][r] = x0.w;
    updT[c + 4][r] = x1.x; updT[c + 5][r] = x1.y;
    updT[c + 6][r] = x1.z; updT[c + 7][r] = x1.w;
  }
  __syncthreads();

  const int rg = t >> 5, cg = t & 31;
  const int rr = rg << 2, cc = cg << 2;
  { // GEMM1 [32x320]x[320x128] + silu -> t1T
    float acc[4][4] = {};
#pragma unroll 4
    for (int k = 0; k < 2 * Hd + Fd; ++k) {
      float4 uv = *(const float4*)&updT[k][rr];
      float4 wv = *(const float4*)&Wm1[k * Hd + cc];
      FMA16(acc, uv, wv)
    }
    float4 b1 = *(const float4*)&bm1[cc];
    float bb1[4] = {b1.x, b1.y, b1.z, b1.w};
#pragma unroll
    for (int a = 0; a < 4; ++a)
#pragma unroll
      for (int b = 0; b < 4; ++b) {
        const float z = acc[a][b] + bb1[b];
        t1T[cc + b][rr + a] = z / (1.0f + __expf(-z));
      }
  }
  __syncthreads();
  { // GEMM2 [32x128]x[128x128] + residual + LayerNorm
    float acc[4][4] = {};
#pragma unroll 4
    for (int k = 0; k < Hd; ++k) {
      float4 uv = *(const float4*)&t1T[k][rr];
      float4 wv = *(const float4*)&Wm2[k * Hd + cc];
      FMA16(acc, uv, wv)
    }
    float4 b2 = *(const float4*)&bm2[cc];
    float bb2[4] = {b2.x, b2.y, b2.z, b2.w};
    float v[4][4];
#pragma unroll
    for (int b = 0; b < 4; ++b) {
      float4 hres = *(const float4*)&updT[cc + b][rr];  // residual = staged hidden
      v[0][b] = hres.x + acc[0][b] + bb2[b];
      v[1][b] = hres.y + acc[1][b] + bb2[b];
      v[2][b] = hres.z + acc[2][b] + bb2[b];
      v[3][b] = hres.w + acc[3][b] + bb2[b];
    }
    float4 gv = *(const float4*)&g[cc];
    float4 bev = *(const float4*)&be[cc];
    float gg[4] = {gv.x, gv.y, gv.z, gv.w};
    float eb[4] = {bev.x, bev.y, bev.z, bev.w};
#pragma unroll
    for (int a = 0; a < 4; ++a) {
      float sm = v[a][0] + v[a][1] + v[a][2] + v[a][3];
      float s2 = 0.f;
#pragma unroll
      for (int b = 0; b < 4; ++b) s2 = fmaf(v[a][b], v[a][b], s2);
#pragma unroll
      for (int m = 1; m < 32; m <<= 1) {
        sm += __shfl_xor(sm, m);
        s2 += __shfl_xor(s2, m);
      }
      const float mean = sm * (1.0f / 128.0f);
      const float var = fmaxf(s2 * (1.0f / 128.0f) - mean * mean, 0.0f);
      const float rstd = rsqrtf(var + 1e-5f);
      float4 o;
      o.x = (v[a][0] - mean) * rstd * gg[0] + eb[0];
      o.y = (v[a][1] - mean) * rstd * gg[1] + eb[1];
      o.z = (v[a][2] - mean) * rstd * gg[2] + eb[2];
      o.w = (v[a][3] - mean) * rstd * gg[3] + eb[3];
      *(float4*)&hout[(size_t)(r0 + rr + a) * Hd + cc] = o;
    }
  }
}

// ---------------- readout: softplus(silu([h,x]@Wr1+b)@Wr2+b) ----------------
__global__ __launch_bounds__(256) void k_out(const float* __restrict__ x,
    const float* __restrict__ hin, const float* __restrict__ Wr1,
    const float* __restrict__ br1, const float* __restrict__ Wr2,
    const float* __restrict__ br2, float* __restrict__ out) {
  __shared__ float rT[Hd + Fd][US];  // 192 x 36 (27 KB)
  const int t = threadIdx.x;
  const int r0 = blockIdx.x * RB;
  {
    const int r = t >> 3, s = t & 7;
    const int i = r0 + r;
    const float* hr = hin + (size_t)i * Hd + (s << 4);
#pragma unroll
    for (int u = 0; u < 4; ++u) {
      float4 v = *(const float4*)(hr + (u << 2));
      const int c = (s << 4) + (u << 2);
      rT[c + 0][r] = v.x; rT[c + 1][r] = v.y;
      rT[c + 2][r] = v.z; rT[c + 3][r] = v.w;
    }
    const float* xr = x + (size_t)i * Fd + (s << 3);
    float4 x0 = *(const float4*)(xr);
    float4 x1 = *(const float4*)(xr + 4);
    const int c = Hd + (s << 3);
    rT[c + 0][r] = x0.x; rT[c + 1][r] = x0.y;
    rT[c + 2][r] = x0.z; rT[c + 3][r] = x0.w;
    rT[c + 4][r] = x1.x; rT[c + 5][r] = x1.y;
    rT[c + 6][r] = x1.z; rT[c + 7][r] = x1.w;
  }
  __syncthreads();
  const int rg = t >> 5, cg = t & 31;
  const int rr = rg << 2, cc = cg << 2;
  float acc[4][4] = {};
#pragma unroll 4
  for (int k = 0; k < Hd + Fd; ++k) {
    float4 uv = *(const float4*)&rT[k][rr];
    float4 wv = *(const float4*)&Wr1[k * Hd + cc];
    FMA16(acc, uv, wv)
  }
  float4 b1 = *(const float4*)&br1[cc];
  float bb1[4] = {b1.x, b1.y, b1.z, b1.w};
  float4 w2 = *(const float4*)&Wr2[cc];
  float ww[4] = {w2.x, w2.y, w2.z, w2.w};
  float part[4];
#pragma unroll
  for (int a = 0; a < 4; ++a) {
    part[a] = 0.f;
#pragma unroll
    for (int b = 0; b < 4; ++b) {
      const float z = acc[a][b] + bb1[b];
      const float sil = z / (1.0f + __expf(-z));
      part[a] = fmaf(sil, ww[b], part[a]);
    }
  }
#pragma unroll
  for (int m = 1; m < 32; m <<= 1) {
#pragma unroll
    for (int a = 0; a < 4; ++a) part[a] += __shfl_xor(part[a], m);
  }
  if (cg == 0) {
    const float bias = br2[0];
#pragma unroll
    for (int a = 0; a < 4; ++a) {
      const float rv = part[a] + bias;
      out[r0 + rr + a] = fmaxf(rv, 0.0f) + log1pf(__expf(-fabsf(rv)));
    }
  }
}

extern "C" void kernel_launch(void* const* d_in, const int* in_sizes, int n_in,
                              void* d_out, int out_size, void* d_ws, size_t ws_size,
                              hipStream_t stream) {
  const float* x    = (const float*)d_in[0];
  const float* W_in = (const float*)d_in[1];
  const float* b_in = (const float*)d_in[2];
  const float* W_m1 = (const float*)d_in[3];
  const float* b_m1 = (const float*)d_in[4];
  const float* W_m2 = (const float*)d_in[5];
  const float* b_m2 = (const float*)d_in[6];
  const float* ln_g = (const float*)d_in[7];
  const float* ln_b = (const float*)d_in[8];
  const float* W_r1 = (const float*)d_in[9];
  const float* b_r1 = (const float*)d_in[10];
  const float* W_r2 = (const float*)d_in[11];
  const float* b_r2 = (const float*)d_in[12];
  float* out = (float*)d_out;

  char* ws = (char*)d_ws;
  const size_t MB = (size_t)1 << 20;
  float*          hidA = (float*)(ws);                 // 8 MB
  float*          hidB = (float*)(ws + 8 * MB);        // 8 MB
  short*          xbhi = (short*)(ws + 16 * MB);       // 2 MB
  short*          xblo = (short*)(ws + 18 * MB);       // 2 MB
  unsigned short* nidx = (unsigned short*)(ws + 20 * MB);  // 1 MB
  float*          nw   = (float*)(ws + 21 * MB);       // 2 MB
  float*          sq   = (float*)(ws + 23 * MB);       // 64 KB

  k_input<<<dim3(Nn / 2), dim3(256), 0, stream>>>(x, W_in, b_in, hidA, sq);
  k_prep<<<dim3(Nn * 8 / 256), dim3(256), 0, stream>>>(x, xbhi, xblo);
  k_knn<<<dim3(Nn / 32), dim3(256), 0, stream>>>(xbhi, xblo, sq, nidx, nw);
  k_step<<<dim3(Nn / RB), dim3(256), 0, stream>>>(x, hidA, nidx, nw, W_m1, b_m1,
                                                  W_m2, b_m2, ln_g, ln_b, hidB);
  k_step<<<dim3(Nn / RB), dim3(256), 0, stream>>>(x, hidB, nidx, nw, W_m1, b_m1,
                                                  W_m2, b_m2, ln_g, ln_b, hidA);
  k_out<<<dim3(Nn / RB), dim3(256), 0, stream>>>(x, hidA, W_r1, b_r1, W_r2, b_r2, out);
}

// Round 8
// 785.632 us; speedup vs baseline: 1.2691x; 1.2691x over previous
//
#include <hip/hip_runtime.h>
#include <math.h>

#define Nn 16384
#define Fd 64
#define Hd 128
#define Kk 32

typedef short bfrag __attribute__((ext_vector_type(8)));    // 8 bf16 = 4 VGPR
typedef float f32x16 __attribute__((ext_vector_type(16)));  // MFMA 32x32 acc
typedef unsigned long long ull;

#define FMA16(acc, qv, pv) \
  acc[0][0]=fmaf(qv.x,pv.x,acc[0][0]); acc[0][1]=fmaf(qv.x,pv.y,acc[0][1]); \
  acc[0][2]=fmaf(qv.x,pv.z,acc[0][2]); acc[0][3]=fmaf(qv.x,pv.w,acc[0][3]); \
  acc[1][0]=fmaf(qv.y,pv.x,acc[1][0]); acc[1][1]=fmaf(qv.y,pv.y,acc[1][1]); \
  acc[1][2]=fmaf(qv.y,pv.z,acc[1][2]); acc[1][3]=fmaf(qv.y,pv.w,acc[1][3]); \
  acc[2][0]=fmaf(qv.z,pv.x,acc[2][0]); acc[2][1]=fmaf(qv.z,pv.y,acc[2][1]); \
  acc[2][2]=fmaf(qv.z,pv.z,acc[2][2]); acc[2][3]=fmaf(qv.z,pv.w,acc[2][3]); \
  acc[3][0]=fmaf(qv.w,pv.x,acc[3][0]); acc[3][1]=fmaf(qv.w,pv.y,acc[3][1]); \
  acc[3][2]=fmaf(qv.w,pv.z,acc[3][2]); acc[3][3]=fmaf(qv.w,pv.w,acc[3][3]);

// ---------------- hidden0 = x @ W_in + b_in ; sq[i] = sum(x_i^2) ----------------
__global__ __launch_bounds__(256) void k_input(const float* __restrict__ x,
    const float* __restrict__ W, const float* __restrict__ b,
    float* __restrict__ hid, float* __restrict__ sq) {
  const int t = threadIdx.x;
  const int i = (blockIdx.x << 1) + (t >> 7);
  const int h = t & 127;
  const float* xr = x + (size_t)i * Fd;
  float acc = 0.f, s = 0.f;
#pragma unroll 8
  for (int f = 0; f < Fd; ++f) {
    float xv = xr[f];
    acc = fmaf(xv, W[f * Hd + h], acc);
    s = fmaf(xv, xv, s);
  }
  hid[(size_t)i * Hd + h] = acc + b[h];
  if (h == 0) sq[i] = s;
}

// ------------- precompute x as bf16 hi/lo in MFMA-fragment order -------------
__global__ __launch_bounds__(256) void k_prep(const float* __restrict__ x,
    short* __restrict__ xh, short* __restrict__ xl) {
  const int gid = blockIdx.x * 256 + threadIdx.x;
  const int p = gid >> 3, sub = gid & 7;
  const float* src = x + (size_t)p * Fd + sub * 8;
  float4 v0 = *(const float4*)src;
  float4 v1 = *(const float4*)(src + 4);
  float vv[8] = {v0.x, v0.y, v0.z, v0.w, v1.x, v1.y, v1.z, v1.w};
  bfrag hi, lo;
#pragma unroll
  for (int j = 0; j < 8; ++j) {
    unsigned u = __float_as_uint(vv[j]);
    unsigned r = u + 0x7fffu + ((u >> 16) & 1u);
    unsigned short hb = (unsigned short)(r >> 16);
    float hf = __uint_as_float((unsigned)hb << 16);
    float lof = vv[j] - hf;
    unsigned ul = __float_as_uint(lof);
    unsigned rl = ul + 0x7fffu + ((ul >> 16) & 1u);
    hi[j] = (short)hb;
    lo[j] = (short)(rl >> 16);
  }
  const size_t o = (size_t)(p >> 5) * 2048 + (size_t)sub * 256 + (size_t)(p & 31) * 8;
  *(bfrag*)(xh + o) = hi;
  *(bfrag*)(xl + o) = lo;
}

// ---------------- KNN: MFMA distance GEMM + wave-parallel sorted top-32 ----------------
// 256 thr (4 waves), 32 queries/block, 128-pt tiles, grid 512 = 2 blocks/CU.
// Per wave: 8 queries; each query's top-32 is a SORTED per-lane register list
// (lanes 0-31). Filter = 1 float cmp + ballot; insert = rank via popcount +
// shfl_up shift (~14 ops). Keys pack (d2bits<<16|idx): strict total order ->
// deterministic, tie-break = lower index. No atomics, no LDS queues.
#define DST 129
#define KEYBIG ((((ull)0x7149F2CAu) << 16) | 0xFFFFull)   // pack(1e30f, 0xFFFF)

__global__ __launch_bounds__(256, 2) void k_knn(const short* __restrict__ xbhi,
    const short* __restrict__ xblo, const float* __restrict__ sq,
    unsigned short* __restrict__ nidx, float* __restrict__ nw) {
  __shared__ __align__(16) float Dt[2][32 * DST];   // d2 tiles, dbuf (33 KB)
  __shared__ __align__(16) float sqq_s[32];

  const int t = threadIdx.x;
  const int w = t >> 6;
  const int lane = t & 63;
  const int h = lane >> 5;
  const int col = lane & 31;
  const int qg0 = blockIdx.x * 32;
  const int selfTileIdx = (int)(blockIdx.x >> 2);   // 32 queries | 128-pt tiles

  if (t < 32) sqq_s[t] = sq[qg0 + t];

  ull topv[8], thr[8];
  float thrD[8];

  const char* xh = (const char*)xbhi;
  const char* xl = (const char*)xblo;

  // A fragments (queries, hi+lo): 32 VGPR
  bfrag ahi[4], alo[4];
  {
    const size_t a0 = (size_t)blockIdx.x * 4096 + (size_t)lane * 16;
#pragma unroll
    for (int s = 0; s < 4; ++s) {
      ahi[s] = *(const bfrag*)(xh + a0 + s * 1024);
      alo[s] = *(const bfrag*)(xl + a0 + s * 1024);
    }
  }
  asm volatile("" :: "v"(ahi[0]), "v"(ahi[1]), "v"(ahi[2]), "v"(ahi[3]),
                     "v"(alo[0]), "v"(alo[1]), "v"(alo[2]), "v"(alo[3]));
  __syncthreads();

#define LOADB(TL, BH, BL, SPD) { \
  const size_t bb_ = (size_t)((TL) * 4 + w) * 4096 + (size_t)lane * 16; \
  _Pragma("unroll") for (int s_ = 0; s_ < 4; ++s_) { \
    BH[s_] = *(const bfrag*)(xh + bb_ + s_ * 1024); \
    BL[s_] = *(const bfrag*)(xl + bb_ + s_ * 1024); } \
  SPD = sq[(TL) * 128 + w * 32 + col]; }

#define PIN(BH, BL) asm volatile("" :: "v"(BH[0]), "v"(BH[1]), "v"(BH[2]), "v"(BH[3]), \
                                       "v"(BL[0]), "v"(BL[1]), "v"(BL[2]), "v"(BL[3]));

#define MFMA12(A0, BH, BL) { \
  _Pragma("unroll") for (int s_ = 0; s_ < 4; ++s_) \
    A0 = __builtin_amdgcn_mfma_f32_32x32x16_bf16(ahi[s_], BH[s_], A0, 0, 0, 0); \
  _Pragma("unroll") for (int s_ = 0; s_ < 4; ++s_) \
    A0 = __builtin_amdgcn_mfma_f32_32x32x16_bf16(ahi[s_], BL[s_], A0, 0, 0, 0); \
  _Pragma("unroll") for (int s_ = 0; s_ < 4; ++s_) \
    A0 = __builtin_amdgcn_mfma_f32_32x32x16_bf16(alo[s_], BH[s_], A0, 0, 0, 0); }

  // d2 = sqq[row] + sqp - 2*dot ; 2-way bank pattern (free) on write
#define WRITED2(ACC, SPv, QB) { \
  _Pragma("unroll") for (int r_ = 0; r_ < 16; ++r_) { \
    const int row_ = (r_ & 3) + 8 * (r_ >> 2) + 4 * h; \
    Dt[QB][row_ * DST + w * 32 + col] = sqq_s[row_] + (SPv)-2.0f * ACC[r_]; \
  } }

  // rank-insert into sorted per-lane list (keys unique or safely duplicated)
#define INS(S, KEY) { \
  if ((KEY) < thr[S]) { \
    const ull bel_ = __ballot(topv[S] < (KEY)); \
    const int r_ = __popcll(bel_); \
    const ull up2_ = __shfl_up(topv[S], 1); \
    if (lane < 32) { \
      if (lane > r_) topv[S] = up2_; \
      else if (lane == r_) topv[S] = (KEY); } \
    thr[S] = __shfl(topv[S], 31); \
    thrD[S] = __uint_as_float((unsigned)(thr[S] >> 16)); \
  } }

#define SCAN(TL, QB) { \
  const int p0g_ = (TL) * 128; \
  const bool selfT_ = ((TL) == selfTileIdx); \
  _Pragma("unroll") for (int s_ = 0; s_ < 8; ++s_) { \
    const int q_ = w * 8 + s_; \
    float d0_ = fmaxf(Dt[QB][q_ * DST + lane], 0.f); \
    float d1_ = fmaxf(Dt[QB][q_ * DST + 64 + lane], 0.f); \
    if (selfT_) { \
      if (p0g_ + lane == qg0 + q_) d0_ = 1e30f; \
      if (p0g_ + 64 + lane == qg0 + q_) d1_ = 1e30f; \
    } \
    ull m0_ = __ballot(d0_ <= thrD[s_]); \
    ull m1_ = __ballot(d1_ <= thrD[s_]); \
    while (m0_) { const int b_ = (int)__builtin_ctzll(m0_); m0_ &= m0_ - 1; \
      const float dv_ = __shfl(d0_, b_); \
      const ull key_ = ((ull)__float_as_uint(dv_) << 16) | (unsigned)(p0g_ + b_); \
      INS(s_, key_) } \
    while (m1_) { const int b_ = (int)__builtin_ctzll(m1_); m1_ &= m1_ - 1; \
      const float dv_ = __shfl(d1_, b_); \
      const ull key_ = ((ull)__float_as_uint(dv_) << 16) | (unsigned)(p0g_ + 64 + b_); \
      INS(s_, key_) } \
  } }

#define STEP(TL, BH, BL, SPC, NBH, NBL, NSPC) { \
  const int tl_ = (TL); \
  if (tl_ + 1 < 128) LOADB(tl_ + 1, NBH, NBL, NSPC) \
  f32x16 a0_; \
  _Pragma("unroll") for (int i_ = 0; i_ < 16; ++i_) a0_[i_] = 0.f; \
  MFMA12(a0_, BH, BL) \
  PIN(NBH, NBL) \
  WRITED2(a0_, SPC, (tl_) & 1) \
  __syncthreads(); \
  SCAN(tl_, (tl_) & 1) }

  bfrag bhA[4], blA[4], bhB[4], blB[4];
  float spA = 0.f, spB = 0.f;

  // ---- tile 0: seed (sort p=0..31) + insert p=32..127 ----
  LOADB(0, bhA, blA, spA)
  {
    f32x16 a0_;
#pragma unroll
    for (int i_ = 0; i_ < 16; ++i_) a0_[i_] = 0.f;
    MFMA12(a0_, bhA, blA)
    LOADB(1, bhB, blB, spB)
    PIN(bhB, blB)
    WRITED2(a0_, spA, 0)
    __syncthreads();
    const bool selfT_ = (0 == selfTileIdx);
#pragma unroll
    for (int s_ = 0; s_ < 8; ++s_) {
      const int q_ = w * 8 + s_;
      float d0_ = fmaxf(Dt[0][q_ * DST + lane], 0.f);
      float d1_ = fmaxf(Dt[0][q_ * DST + 64 + lane], 0.f);
      if (selfT_) {
        if (lane == qg0 + q_) d0_ = 1e30f;
        if (64 + lane == qg0 + q_) d1_ = 1e30f;
      }
      // seed from points 0..31, bitonic sort ascending over lanes 0-31
      ull v_ = (lane < 32)
          ? (((ull)__float_as_uint(d0_) << 16) | (unsigned)lane)
          : KEYBIG;
#pragma unroll
      for (int k2_ = 2; k2_ <= 32; k2_ <<= 1) {
#pragma unroll
        for (int j_ = k2_ >> 1; j_ >= 1; j_ >>= 1) {
          const ull o_ = __shfl_xor(v_, j_);
          const bool up_ = ((lane & k2_ & 31) == 0);
          const bool mn_ = (((lane & j_) == 0) == up_);
          v_ = mn_ ? (o_ < v_ ? o_ : v_) : (o_ > v_ ? o_ : v_);
        }
      }
      topv[s_] = (lane < 32) ? v_ : KEYBIG;
      thr[s_] = __shfl(v_, 31);
      thrD[s_] = __uint_as_float((unsigned)(thr[s_] >> 16));
      ull m0_ = __ballot(d0_ <= thrD[s_]) & 0xFFFFFFFF00000000ull;  // p=32..63
      ull m1_ = __ballot(d1_ <= thrD[s_]);                          // p=64..127
      while (m0_) { const int b_ = (int)__builtin_ctzll(m0_); m0_ &= m0_ - 1;
        const float dv_ = __shfl(d0_, b_);
        const ull key_ = ((ull)__float_as_uint(dv_) << 16) | (unsigned)b_;
        INS(s_, key_) }
      while (m1_) { const int b_ = (int)__builtin_ctzll(m1_); m1_ &= m1_ - 1;
        const float dv_ = __shfl(d1_, b_);
        const ull key_ = ((ull)__float_as_uint(dv_) << 16) | (unsigned)(64 + b_);
        INS(s_, key_) }
    }
  }

  // ---- tiles 1..127 ----
  for (int tp = 1; tp < 127; tp += 2) {
    STEP(tp, bhB, blB, spB, bhA, blA, spA)
    STEP(tp + 1, bhA, blA, spA, bhB, blB, spB)
  }
  STEP(127, bhB, blB, spB, bhA, blA, spA)

  // ---- finalize: softmax(-2d) over sorted list (min = lane 0) ----
#pragma unroll
  for (int s_ = 0; s_ < 8; ++s_) {
    const int q_ = w * 8 + s_;
    const float d_ = sqrtf(__uint_as_float((unsigned)(topv[s_] >> 16)));
    const float mn_ = __shfl(d_, 0);
    const float e_ = __expf((mn_ - d_) * 2.0f);
    float s2_ = e_;
#pragma unroll
    for (int m_ = 1; m_ < 32; m_ <<= 1) s2_ += __shfl_xor(s2_, m_);
    if (lane < 32) {
      nw[(qg0 + q_) * Kk + lane] = e_ / s2_;
      nidx[(qg0 + q_) * Kk + lane] = (unsigned short)(topv[s_] & 0xFFFFull);
    }
  }
#undef LOADB
#undef PIN
#undef MFMA12
#undef WRITED2
#undef INS
#undef SCAN
#undef STEP
}

// ---------------- one message-pass step, fused: gather+MLP+LN ----------------
#define RB 32
#define US 36

__global__ __launch_bounds__(256) void k_step(const float* __restrict__ x,
    const float* __restrict__ hin, const unsigned short* __restrict__ nidx,
    const float* __restrict__ nw, const float* __restrict__ Wm1,
    const float* __restrict__ bm1, const float* __restrict__ Wm2,
    const float* __restrict__ bm2, const float* __restrict__ g,
    const float* __restrict__ be, float* __restrict__ hout) {
  __shared__ float updT[2 * Hd + Fd][US];  // upd_in transposed: 320 x 36 (46 KB)
  __shared__ float t1T[Hd][US];            // silu(GEMM1) transposed (18 KB)
  const int t = threadIdx.x;
  const int r0 = blockIdx.x * RB;

  { // stage: hidden | agg (gather) | x, all transposed
    const int r = t >> 3, s = t & 7;
    const int i = r0 + r;
    const float* hr = hin + (size_t)i * Hd + (s << 4);
#pragma unroll
    for (int u = 0; u < 4; ++u) {
      float4 v = *(const float4*)(hr + (u << 2));
      const int c = (s << 4) + (u << 2);
      updT[c + 0][r] = v.x; updT[c + 1][r] = v.y;
      updT[c + 2][r] = v.z; updT[c + 3][r] = v.w;
    }
    float a[16];
#pragma unroll
    for (int u = 0; u < 16; ++u) a[u] = 0.f;
    const unsigned short* ir = nidx + i * Kk;
    const float* wr = nw + i * Kk;
    for (int k = 0; k < Kk; ++k) {
      const float wk = wr[k];
      const float* hv = hin + (size_t)ir[k] * Hd + (s << 4);
#pragma unroll
      for (int u = 0; u < 4; ++u) {
        float4 v = *(const float4*)(hv + (u << 2));
        a[(u << 2) + 0] = fmaf(wk, v.x, a[(u << 2) + 0]);
        a[(u << 2) + 1] = fmaf(wk, v.y, a[(u << 2) + 1]);
        a[(u << 2) + 2] = fmaf(wk, v.z, a[(u << 2) + 2]);
        a[(u << 2) + 3] = fmaf(wk, v.w, a[(u << 2) + 3]);
      }
    }
#pragma unroll
    for (int u = 0; u < 16; ++u) updT[Hd + (s << 4) + u][r] = a[u];
    const float* xr = x + (size_t)i * Fd + (s << 3);
    float4 x0 = *(const float4*)(xr);
    float4 x1 = *(const float4*)(xr + 4);
    const int c = 2 * Hd + (s << 3);
    updT[c + 0][r] = x0.x; updT[c + 1][r] = x0.y;
    updT[c + 2][r] = x0.z; updT[c + 3][r] = x0.w;
    updT[c + 4][r] = x1.x; updT[c + 5][r] = x1.y;
    updT[c + 6][r] = x1.z; updT[c + 7][r] = x1.w;
  }
  __syncthreads();

  const int rg = t >> 5, cg = t & 31;
  const int rr = rg << 2, cc = cg << 2;
  { // GEMM1 [32x320]x[320x128] + silu -> t1T
    float acc[4][4] = {};
#pragma unroll 4
    for (int k = 0; k < 2 * Hd + Fd; ++k) {
      float4 uv = *(const float4*)&updT[k][rr];
      float4 wv = *(const float4*)&Wm1[k * Hd + cc];
      FMA16(acc, uv, wv)
    }
    float4 b1 = *(const float4*)&bm1[cc];
    float bb1[4] = {b1.x, b1.y, b1.z, b1.w};
#pragma unroll
    for (int a = 0; a < 4; ++a)
#pragma unroll
      for (int b = 0; b < 4; ++b) {
        const float z = acc[a][b] + bb1[b];
        t1T[cc + b][rr + a] = z / (1.0f + __expf(-z));
      }
  }
  __syncthreads();
  { // GEMM2 [32x128]x[128x128] + residual + LayerNorm
    float acc[4][4] = {};
#pragma unroll 4
    for (int k = 0; k < Hd; ++k) {
      float4 uv = *(const float4*)&t1T[k][rr];
      float4 wv = *(const float4*)&Wm2[k * Hd + cc];
      FMA16(acc, uv, wv)
    }
    float4 b2 = *(const float4*)&bm2[cc];
    float bb2[4] = {b2.x, b2.y, b2.z, b2.w};
    float v[4][4];
#pragma unroll
    for (int b = 0; b < 4; ++b) {
      float4 hres = *(const float4*)&updT[cc + b][rr];  // residual = staged hidden
      v[0][b] = hres.x + acc[0][b] + bb2[b];
      v[1][b] = hres.y + acc[1][b] + bb2[b];
      v[2][b] = hres.z + acc[2][b] + bb2[b];
      v[3][b] = hres.w + acc[3][b] + bb2[b];
    }
    float4 gv = *(const float4*)&g[cc];
    float4 bev = *(const float4*)&be[cc];
    float gg[4] = {gv.x, gv.y, gv.z, gv.w};
    float eb[4] = {bev.x, bev.y, bev.z, bev.w};
#pragma unroll
    for (int a = 0; a < 4; ++a) {
      float sm = v[a][0] + v[a][1] + v[a][2] + v[a][3];
      float s2 = 0.f;
#pragma unroll
      for (int b = 0; b < 4; ++b) s2 = fmaf(v[a][b], v[a][b], s2);
#pragma unroll
      for (int m = 1; m < 32; m <<= 1) {
        sm += __shfl_xor(sm, m);
        s2 += __shfl_xor(s2, m);
      }
      const float mean = sm * (1.0f / 128.0f);
      const float var = fmaxf(s2 * (1.0f / 128.0f) - mean * mean, 0.0f);
      const float rstd = rsqrtf(var + 1e-5f);
      float4 o;
      o.x = (v[a][0] - mean) * rstd * gg[0] + eb[0];
      o.y = (v[a][1] - mean) * rstd * gg[1] + eb[1];
      o.z = (v[a][2] - mean) * rstd * gg[2] + eb[2];
      o.w = (v[a][3] - mean) * rstd * gg[3] + eb[3];
      *(float4*)&hout[(size_t)(r0 + rr + a) * Hd + cc] = o;
    }
  }
}

// ---------------- readout: softplus(silu([h,x]@Wr1+b)@Wr2+b) ----------------
__global__ __launch_bounds__(256) void k_out(const float* __restrict__ x,
    const float* __restrict__ hin, const float* __restrict__ Wr1,
    const float* __restrict__ br1, const float* __restrict__ Wr2,
    const float* __restrict__ br2, float* __restrict__ out) {
  __shared__ float rT[Hd + Fd][US];  // 192 x 36 (27 KB)
  const int t = threadIdx.x;
  const int r0 = blockIdx.x * RB;
  {
    const int r = t >> 3, s = t & 7;
    const int i = r0 + r;
    const float* hr = hin + (size_t)i * Hd + (s << 4);
#pragma unroll
    for (int u = 0; u < 4; ++u) {
      float4 v = *(const float4*)(hr + (u << 2));
      const int c = (s << 4) + (u << 2);
      rT[c + 0][r] = v.x; rT[c + 1][r] = v.y;
      rT[c + 2][r] = v.z; rT[c + 3][r] = v.w;
    }
    const float* xr = x + (size_t)i * Fd + (s << 3);
    float4 x0 = *(const float4*)(xr);
    float4 x1 = *(const float4*)(xr + 4);
    const int c = Hd + (s << 3);
    rT[c + 0][r] = x0.x; rT[c + 1][r] = x0.y;
    rT[c + 2][r] = x0.z; rT[c + 3][r] = x0.w;
    rT[c + 4][r] = x1.x; rT[c + 5][r] = x1.y;
    rT[c + 6][r] = x1.z; rT[c + 7][r] = x1.w;
  }
  __syncthreads();
  const int rg = t >> 5, cg = t & 31;
  const int rr = rg << 2, cc = cg << 2;
  float acc[4][4] = {};
#pragma unroll 4
  for (int k = 0; k < Hd + Fd; ++k) {
    float4 uv = *(const float4*)&rT[k][rr];
    float4 wv = *(const float4*)&Wr1[k * Hd + cc];
    FMA16(acc, uv, wv)
  }
  float4 b1 = *(const float4*)&br1[cc];
  float bb1[4] = {b1.x, b1.y, b1.z, b1.w};
  float4 w2 = *(const float4*)&Wr2[cc];
  float ww[4] = {w2.x, w2.y, w2.z, w2.w};
  float part[4];
#pragma unroll
  for (int a = 0; a < 4; ++a) {
    part[a] = 0.f;
#pragma unroll
    for (int b = 0; b < 4; ++b) {
      const float z = acc[a][b] + bb1[b];
      const float sil = z / (1.0f + __expf(-z));
      part[a] = fmaf(sil, ww[b], part[a]);
    }
  }
#pragma unroll
  for (int m = 1; m < 32; m <<= 1) {
#pragma unroll
    for (int a = 0; a < 4; ++a) part[a] += __shfl_xor(part[a], m);
  }
  if (cg == 0) {
    const float bias = br2[0];
#pragma unroll
    for (int a = 0; a < 4; ++a) {
      const float rv = part[a] + bias;
      out[r0 + rr + a] = fmaxf(rv, 0.0f) + log1pf(__expf(-fabsf(rv)));
    }
  }
}

extern "C" void kernel_launch(void* const* d_in, const int* in_sizes, int n_in,
                              void* d_out, int out_size, void* d_ws, size_t ws_size,
                              hipStream_t stream) {
  const float* x    = (const float*)d_in[0];
  const float* W_in = (const float*)d_in[1];
  const float* b_in = (const float*)d_in[2];
  const float* W_m1 = (const float*)d_in[3];
  const float* b_m1 = (const float*)d_in[4];
  const float* W_m2 = (const float*)d_in[5];
  const float* b_m2 = (const float*)d_in[6];
  const float* ln_g = (const float*)d_in[7];
  const float* ln_b = (const float*)d_in[8];
  const float* W_r1 = (const float*)d_in[9];
  const float* b_r1 = (const float*)d_in[10];
  const float* W_r2 = (const float*)d_in[11];
  const float* b_r2 = (const float*)d_in[12];
  float* out = (float*)d_out;

  char* ws = (char*)d_ws;
  const size_t MB = (size_t)1 << 20;
  float*          hidA = (float*)(ws);                 // 8 MB
  float*          hidB = (float*)(ws + 8 * MB);        // 8 MB
  short*          xbhi = (short*)(ws + 16 * MB);       // 2 MB
  short*          xblo = (short*)(ws + 18 * MB);       // 2 MB
  unsigned short* nidx = (unsigned short*)(ws + 20 * MB);  // 1 MB
  float*          nw   = (float*)(ws + 21 * MB);       // 2 MB
  float*          sq   = (float*)(ws + 23 * MB);       // 64 KB

  k_input<<<dim3(Nn / 2), dim3(256), 0, stream>>>(x, W_in, b_in, hidA, sq);
  k_prep<<<dim3(Nn * 8 / 256), dim3(256), 0, stream>>>(x, xbhi, xblo);
  k_knn<<<dim3(Nn / 32), dim3(256), 0, stream>>>(xbhi, xblo, sq, nidx, nw);
  k_step<<<dim3(Nn / RB), dim3(256), 0, stream>>>(x, hidA, nidx, nw, W_m1, b_m1,
                                                  W_m2, b_m2, ln_g, ln_b, hidB);
  k_step<<<dim3(Nn / RB), dim3(256), 0, stream>>>(x, hidB, nidx, nw, W_m1, b_m1,
                                                  W_m2, b_m2, ln_g, ln_b, hidA);
  k_out<<<dim3(Nn / RB), dim3(256), 0, stream>>>(x, hidA, W_r1, b_r1, W_r2, b_r2, out);
}

// Round 9
// 734.673 us; speedup vs baseline: 1.3571x; 1.0694x over previous
//
#include <hip/hip_runtime.h>
#include <math.h>

#define Nn 16384
#define Fd 64
#define Hd 128
#define Kk 32

typedef short bfrag __attribute__((ext_vector_type(8)));    // 8 bf16 = 4 VGPR
typedef float f32x16 __attribute__((ext_vector_type(16)));  // MFMA 32x32 acc
typedef unsigned long long ull;

#define FMA16(acc, qv, pv) \
  acc[0][0]=fmaf(qv.x,pv.x,acc[0][0]); acc[0][1]=fmaf(qv.x,pv.y,acc[0][1]); \
  acc[0][2]=fmaf(qv.x,pv.z,acc[0][2]); acc[0][3]=fmaf(qv.x,pv.w,acc[0][3]); \
  acc[1][0]=fmaf(qv.y,pv.x,acc[1][0]); acc[1][1]=fmaf(qv.y,pv.y,acc[1][1]); \
  acc[1][2]=fmaf(qv.y,pv.z,acc[1][2]); acc[1][3]=fmaf(qv.y,pv.w,acc[1][3]); \
  acc[2][0]=fmaf(qv.z,pv.x,acc[2][0]); acc[2][1]=fmaf(qv.z,pv.y,acc[2][1]); \
  acc[2][2]=fmaf(qv.z,pv.z,acc[2][2]); acc[2][3]=fmaf(qv.z,pv.w,acc[2][3]); \
  acc[3][0]=fmaf(qv.w,pv.x,acc[3][0]); acc[3][1]=fmaf(qv.w,pv.y,acc[3][1]); \
  acc[3][2]=fmaf(qv.w,pv.z,acc[3][2]); acc[3][3]=fmaf(qv.w,pv.w,acc[3][3]);

// ---------------- hidden0 = x @ W_in + b_in ; sq[i] = sum(x_i^2) ----------------
__global__ __launch_bounds__(256) void k_input(const float* __restrict__ x,
    const float* __restrict__ W, const float* __restrict__ b,
    float* __restrict__ hid, float* __restrict__ sq) {
  const int t = threadIdx.x;
  const int i = (blockIdx.x << 1) + (t >> 7);
  const int h = t & 127;
  const float* xr = x + (size_t)i * Fd;
  float acc = 0.f, s = 0.f;
#pragma unroll 8
  for (int f = 0; f < Fd; ++f) {
    float xv = xr[f];
    acc = fmaf(xv, W[f * Hd + h], acc);
    s = fmaf(xv, xv, s);
  }
  hid[(size_t)i * Hd + h] = acc + b[h];
  if (h == 0) sq[i] = s;
}

// ------------- precompute x as bf16 hi/lo in MFMA-fragment order -------------
__global__ __launch_bounds__(256) void k_prep(const float* __restrict__ x,
    short* __restrict__ xh, short* __restrict__ xl) {
  const int gid = blockIdx.x * 256 + threadIdx.x;
  const int p = gid >> 3, sub = gid & 7;
  const float* src = x + (size_t)p * Fd + sub * 8;
  float4 v0 = *(const float4*)src;
  float4 v1 = *(const float4*)(src + 4);
  float vv[8] = {v0.x, v0.y, v0.z, v0.w, v1.x, v1.y, v1.z, v1.w};
  bfrag hi, lo;
#pragma unroll
  for (int j = 0; j < 8; ++j) {
    unsigned u = __float_as_uint(vv[j]);
    unsigned r = u + 0x7fffu + ((u >> 16) & 1u);
    unsigned short hb = (unsigned short)(r >> 16);
    float hf = __uint_as_float((unsigned)hb << 16);
    float lof = vv[j] - hf;
    unsigned ul = __float_as_uint(lof);
    unsigned rl = ul + 0x7fffu + ((ul >> 16) & 1u);
    hi[j] = (short)hb;
    lo[j] = (short)(rl >> 16);
  }
  const size_t o = (size_t)(p >> 5) * 2048 + (size_t)sub * 256 + (size_t)(p & 31) * 8;
  *(bfrag*)(xh + o) = hi;
  *(bfrag*)(xl + o) = lo;
}

// ---------------- KNN pass 1: split-K partial top-32 ----------------
// Grid 1024: block = (qblk = bid>>1, half = bid&1). 32 queries, 64 tiles of 128
// points (half the sweep). 4 blocks/CU resident (VGPR<=128, LDS 33KB).
// Wave owns 8 queries; top-32 = sorted per-lane register list (lanes 0-31).
// Trimmed insert: readlane broadcast, deferred thr refresh (once per tile/query).
// Keys pack (d2bits<<16|idx): strict total order -> deterministic.
#define DST 129
#define KEYBIG ((((ull)0x7149F2CAu) << 16) | 0xFFFFull)   // pack(1e30f, 0xFFFF)

__global__ __launch_bounds__(256, 2) void k_knn(const short* __restrict__ xbhi,
    const short* __restrict__ xblo, const float* __restrict__ sq,
    ull* __restrict__ part) {
  __shared__ __align__(16) float Dt[2][32 * DST];   // d2 tiles, dbuf (33 KB)
  __shared__ __align__(16) float sqq_s[32];

  const int t = threadIdx.x;
  const int w = t >> 6;
  const int lane = t & 63;
  const int h = lane >> 5;
  const int col = lane & 31;
  const int qblk = (int)(blockIdx.x >> 1);
  const int half = (int)(blockIdx.x & 1);
  const int qg0 = qblk * 32;
  const int t0 = half * 64;                 // global tile range [t0, t0+64)
  const int selfTileG = qblk >> 2;          // global tile holding this query group

  if (t < 32) sqq_s[t] = sq[qg0 + t];

  ull topv[8];
  float thrD[8];

  const char* xh = (const char*)xbhi;
  const char* xl = (const char*)xblo;

  // A fragments (queries, hi+lo): 32 VGPR
  bfrag ahi[4], alo[4];
  {
    const size_t a0 = (size_t)qblk * 4096 + (size_t)lane * 16;
#pragma unroll
    for (int s = 0; s < 4; ++s) {
      ahi[s] = *(const bfrag*)(xh + a0 + s * 1024);
      alo[s] = *(const bfrag*)(xl + a0 + s * 1024);
    }
  }
  asm volatile("" :: "v"(ahi[0]), "v"(ahi[1]), "v"(ahi[2]), "v"(ahi[3]),
                     "v"(alo[0]), "v"(alo[1]), "v"(alo[2]), "v"(alo[3]));
  __syncthreads();

#define LOADB(TL, BH, BL, SPD) { \
  const size_t bb_ = (size_t)((TL) * 4 + w) * 4096 + (size_t)lane * 16; \
  _Pragma("unroll") for (int s_ = 0; s_ < 4; ++s_) { \
    BH[s_] = *(const bfrag*)(xh + bb_ + s_ * 1024); \
    BL[s_] = *(const bfrag*)(xl + bb_ + s_ * 1024); } \
  SPD = sq[(TL) * 128 + w * 32 + col]; }

#define PIN(BH, BL) asm volatile("" :: "v"(BH[0]), "v"(BH[1]), "v"(BH[2]), "v"(BH[3]), \
                                       "v"(BL[0]), "v"(BL[1]), "v"(BL[2]), "v"(BL[3]));

#define MFMA12(A0, BH, BL) { \
  _Pragma("unroll") for (int s_ = 0; s_ < 4; ++s_) \
    A0 = __builtin_amdgcn_mfma_f32_32x32x16_bf16(ahi[s_], BH[s_], A0, 0, 0, 0); \
  _Pragma("unroll") for (int s_ = 0; s_ < 4; ++s_) \
    A0 = __builtin_amdgcn_mfma_f32_32x32x16_bf16(ahi[s_], BL[s_], A0, 0, 0, 0); \
  _Pragma("unroll") for (int s_ = 0; s_ < 4; ++s_) \
    A0 = __builtin_amdgcn_mfma_f32_32x32x16_bf16(alo[s_], BH[s_], A0, 0, 0, 0); }

#define WRITED2(ACC, SPv, QB) { \
  _Pragma("unroll") for (int r_ = 0; r_ < 16; ++r_) { \
    const int row_ = (r_ & 3) + 8 * (r_ >> 2) + 4 * h; \
    Dt[QB][row_ * DST + w * 32 + col] = sqq_s[row_] + (SPv)-2.0f * ACC[r_]; \
  } }

  // rank-insert; rank>=32 self-drops; no thr touch (deferred)
#define INS(S, KEY) { \
  const ull up_ = __shfl_up(topv[S], 1); \
  const ull bel_ = __ballot(topv[S] < (KEY)); \
  const int r_ = __popcll(bel_); \
  const bool sh_ = (lane > r_) && (lane < 32); \
  const bool pl_ = (lane == r_) && (lane < 32); \
  topv[S] = sh_ ? up_ : (pl_ ? (KEY) : topv[S]); }

#define REFRESH(S) { \
  const int h_ = __builtin_amdgcn_readlane((int)(topv[S] >> 32), 31); \
  const int l_ = __builtin_amdgcn_readlane((int)(topv[S] & 0xFFFFFFFFull), 31); \
  thrD[S] = __uint_as_float(((unsigned)h_ << 16) | ((unsigned)l_ >> 16)); }

#define SCAN(GT, QB) { \
  const int p0g_ = (GT) * 128; \
  const bool selfT_ = ((GT) == selfTileG); \
  _Pragma("unroll") for (int s_ = 0; s_ < 8; ++s_) { \
    const int q_ = w * 8 + s_; \
    float d0_ = Dt[QB][q_ * DST + lane]; \
    float d1_ = Dt[QB][q_ * DST + 64 + lane]; \
    if (selfT_) { \
      if (p0g_ + lane == qg0 + q_) d0_ = 1e30f; \
      if (p0g_ + 64 + lane == qg0 + q_) d1_ = 1e30f; \
    } \
    ull m0_ = __ballot(d0_ <= thrD[s_]); \
    ull m1_ = __ballot(d1_ <= thrD[s_]); \
    if (m0_ | m1_) { \
      while (m0_) { const int b_ = (int)__builtin_ctzll(m0_); m0_ &= m0_ - 1; \
        const int db_ = __builtin_amdgcn_readlane(__float_as_int(d0_), b_); \
        const ull key_ = ((ull)(unsigned)db_ << 16) | (unsigned)(p0g_ + b_); \
        INS(s_, key_) } \
      while (m1_) { const int b_ = (int)__builtin_ctzll(m1_); m1_ &= m1_ - 1; \
        const int db_ = __builtin_amdgcn_readlane(__float_as_int(d1_), b_); \
        const ull key_ = ((ull)(unsigned)db_ << 16) | (unsigned)(p0g_ + 64 + b_); \
        INS(s_, key_) } \
      REFRESH(s_) \
    } \
  } }

#define STEP(LT, BH, BL, SPC, NBH, NBL, NSPC) { \
  const int lt_ = (LT); const int gT_ = t0 + lt_; \
  if (lt_ + 1 < 64) LOADB(gT_ + 1, NBH, NBL, NSPC) \
  f32x16 a0_; \
  _Pragma("unroll") for (int i_ = 0; i_ < 16; ++i_) a0_[i_] = 0.f; \
  MFMA12(a0_, BH, BL) \
  PIN(NBH, NBL) \
  WRITED2(a0_, SPC, lt_ & 1) \
  __syncthreads(); \
  SCAN(gT_, lt_ & 1) }

  bfrag bhA[4], blA[4], bhB[4], blB[4];
  float spA = 0.f, spB = 0.f;

  // ---- first tile: seed (sort first 32 pts) + insert rest ----
  LOADB(t0, bhA, blA, spA)
  {
    f32x16 a0_;
#pragma unroll
    for (int i_ = 0; i_ < 16; ++i_) a0_[i_] = 0.f;
    MFMA12(a0_, bhA, blA)
    LOADB(t0 + 1, bhB, blB, spB)
    PIN(bhB, blB)
    WRITED2(a0_, spA, 0)
    __syncthreads();
    const int p0g_ = t0 * 128;
    const bool selfT_ = (t0 == selfTileG);
#pragma unroll
    for (int s_ = 0; s_ < 8; ++s_) {
      const int q_ = w * 8 + s_;
      float d0_ = Dt[0][q_ * DST + lane];
      float d1_ = Dt[0][q_ * DST + 64 + lane];
      if (selfT_) {
        if (p0g_ + lane == qg0 + q_) d0_ = 1e30f;
        if (p0g_ + 64 + lane == qg0 + q_) d1_ = 1e30f;
      }
      // seed from first 32 points, bitonic sort ascending over lanes 0-31
      ull v_ = (lane < 32)
          ? (((ull)__float_as_uint(d0_) << 16) | (unsigned)(p0g_ + lane))
          : KEYBIG;
#pragma unroll
      for (int k2_ = 2; k2_ <= 32; k2_ <<= 1) {
#pragma unroll
        for (int j_ = k2_ >> 1; j_ >= 1; j_ >>= 1) {
          const ull o_ = __shfl_xor(v_, j_);
          const bool up_ = ((lane & k2_ & 31) == 0);
          const bool mn_ = (((lane & j_) == 0) == up_);
          v_ = mn_ ? (o_ < v_ ? o_ : v_) : (o_ > v_ ? o_ : v_);
        }
      }
      topv[s_] = (lane < 32) ? v_ : KEYBIG;
      REFRESH(s_)
      ull m0_ = __ballot(d0_ <= thrD[s_]) & 0xFFFFFFFF00000000ull;  // pts 32..63
      ull m1_ = __ballot(d1_ <= thrD[s_]);                          // pts 64..127
      if (m0_ | m1_) {
        while (m0_) { const int b_ = (int)__builtin_ctzll(m0_); m0_ &= m0_ - 1;
          const int db_ = __builtin_amdgcn_readlane(__float_as_int(d0_), b_);
          const ull key_ = ((ull)(unsigned)db_ << 16) | (unsigned)(p0g_ + b_);
          INS(s_, key_) }
        while (m1_) { const int b_ = (int)__builtin_ctzll(m1_); m1_ &= m1_ - 1;
          const int db_ = __builtin_amdgcn_readlane(__float_as_int(d1_), b_);
          const ull key_ = ((ull)(unsigned)db_ << 16) | (unsigned)(p0g_ + 64 + b_);
          INS(s_, key_) }
        REFRESH(s_)
      }
    }
  }

  // ---- local tiles 1..63 (B-register + Dt-buffer ping-pong) ----
  for (int lt = 1; lt < 63; lt += 2) {
    STEP(lt, bhB, blB, spB, bhA, blA, spA)
    STEP(lt + 1, bhA, blA, spA, bhB, blB, spB)
  }
  STEP(63, bhB, blB, spB, bhA, blA, spA)

  // ---- write partial sorted top-32 lists ----
#pragma unroll
  for (int s_ = 0; s_ < 8; ++s_) {
    if (lane < 32)
      part[(size_t)(qg0 + w * 8 + s_) * 64 + half * 32 + lane] = topv[s_];
  }
#undef LOADB
#undef PIN
#undef MFMA12
#undef WRITED2
#undef INS
#undef REFRESH
#undef SCAN
#undef STEP
}

// ---------------- KNN pass 2: merge two sorted-32 lists + softmax ----------------
__global__ __launch_bounds__(256) void k_merge(const ull* __restrict__ part,
    unsigned short* __restrict__ nidx, float* __restrict__ nw) {
  const int t = threadIdx.x;
  const int w = t >> 6;
  const int lane = t & 63;
  const int q = (int)blockIdx.x * 4 + w;
  // lanes 0-31 ascending (half 0), lanes 32-63 = half 1 reversed -> bitonic
  const int src = (lane < 32) ? lane : (95 - lane);
  ull v = part[(size_t)q * 64 + src];
#pragma unroll
  for (int j = 32; j >= 1; j >>= 1) {
    const ull o = __shfl_xor(v, j);
    const bool mn = ((lane & j) == 0);
    v = mn ? (o < v ? o : v) : (o > v ? o : v);
  }
  // lanes 0-31 now hold the global top-32 sorted ascending
  const float d = sqrtf(__uint_as_float((unsigned)(v >> 16)));
  const float mn_ = __shfl(d, 0);
  float e = (lane < 32) ? __expf((mn_ - d) * 2.0f) : 0.f;
  float s2 = e;
#pragma unroll
  for (int m = 1; m < 64; m <<= 1) s2 += __shfl_xor(s2, m);
  if (lane < 32) {
    nw[(size_t)q * Kk + lane] = e / s2;
    nidx[(size_t)q * Kk + lane] = (unsigned short)(v & 0xFFFFull);
  }
}

// ---------------- one message-pass step, fused: gather+MLP+LN ----------------
#define RB 32
#define US 36

__global__ __launch_bounds__(256) void k_step(const float* __restrict__ x,
    const float* __restrict__ hin, const unsigned short* __restrict__ nidx,
    const float* __restrict__ nw, const float* __restrict__ Wm1,
    const float* __restrict__ bm1, const float* __restrict__ Wm2,
    const float* __restrict__ bm2, const float* __restrict__ g,
    const float* __restrict__ be, float* __restrict__ hout) {
  __shared__ float updT[2 * Hd + Fd][US];  // upd_in transposed: 320 x 36 (46 KB)
  __shared__ float t1T[Hd][US];            // silu(GEMM1) transposed (18 KB)
  const int t = threadIdx.x;
  const int r0 = blockIdx.x * RB;

  { // stage: hidden | agg (gather) | x, all transposed
    const int r = t >> 3, s = t & 7;
    const int i = r0 + r;
    const float* hr = hin + (size_t)i * Hd + (s << 4);
#pragma unroll
    for (int u = 0; u < 4; ++u) {
      float4 v = *(const float4*)(hr + (u << 2));
      const int c = (s << 4) + (u << 2);
      updT[c + 0][r] = v.x; updT[c + 1][r] = v.y;
      updT[c + 2][r] = v.z; updT[c + 3][r] = v.w;
    }
    float a[16];
#pragma unroll
    for (int u = 0; u < 16; ++u) a[u] = 0.f;
    const unsigned short* ir = nidx + i * Kk;
    const float* wr = nw + i * Kk;
    for (int k = 0; k < Kk; ++k) {
      const float wk = wr[k];
      const float* hv = hin + (size_t)ir[k] * Hd + (s << 4);
#pragma unroll
      for (int u = 0; u < 4; ++u) {
        float4 v = *(const float4*)(hv + (u << 2));
        a[(u << 2) + 0] = fmaf(wk, v.x, a[(u << 2) + 0]);
        a[(u << 2) + 1] = fmaf(wk, v.y, a[(u << 2) + 1]);
        a[(u << 2) + 2] = fmaf(wk, v.z, a[(u << 2) + 2]);
        a[(u << 2) + 3] = fmaf(wk, v.w, a[(u << 2) + 3]);
      }
    }
#pragma unroll
    for (int u = 0; u < 16; ++u) updT[Hd + (s << 4) + u][r] = a[u];
    const float* xr = x + (size_t)i * Fd + (s << 3);
    float4 x0 = *(const float4*)(xr);
    float4 x1 = *(const float4*)(xr + 4);
    const int c = 2 * Hd + (s << 3);
    updT[c + 0][r] = x0.x; updT[c + 1][r] = x0.y;
    updT[c + 2][r] = x0.z; updT[c + 3][r] = x0.w;
    updT[c + 4][r] = x1.x; updT[c + 5][r] = x1.y;
    updT[c + 6][r] = x1.z; updT[c + 7][r] = x1.w;
  }
  __syncthreads();

  const int rg = t >> 5, cg = t & 31;
  const int rr = rg << 2, cc = cg << 2;
  { // GEMM1 [32x320]x[320x128] + silu -> t1T
    float acc[4][4] = {};
#pragma unroll 4
    for (int k = 0; k < 2 * Hd + Fd; ++k) {
      float4 uv = *(const float4*)&updT[k][rr];
      float4 wv = *(const float4*)&Wm1[k * Hd + cc];
      FMA16(acc, uv, wv)
    }
    float4 b1 = *(const float4*)&bm1[cc];
    float bb1[4] = {b1.x, b1.y, b1.z, b1.w};
#pragma unroll
    for (int a = 0; a < 4; ++a)
#pragma unroll
      for (int b = 0; b < 4; ++b) {
        const float z = acc[a][b] + bb1[b];
        t1T[cc + b][rr + a] = z / (1.0f + __expf(-z));
      }
  }
  __syncthreads();
  { // GEMM2 [32x128]x[128x128] + residual + LayerNorm
    float acc[4][4] = {};
#pragma unroll 4
    for (int k = 0; k < Hd; ++k) {
      float4 uv = *(const float4*)&t1T[k][rr];
      float4 wv = *(const float4*)&Wm2[k * Hd + cc];
      FMA16(acc, uv, wv)
    }
    float4 b2 = *(const float4*)&bm2[cc];
    float bb2[4] = {b2.x, b2.y, b2.z, b2.w};
    float v[4][4];
#pragma unroll
    for (int b = 0; b < 4; ++b) {
      float4 hres = *(const float4*)&updT[cc + b][rr];  // residual = staged hidden
      v[0][b] = hres.x + acc[0][b] + bb2[b];
      v[1][b] = hres.y + acc[1][b] + bb2[b];
      v[2][b] = hres.z + acc[2][b] + bb2[b];
      v[3][b] = hres.w + acc[3][b] + bb2[b];
    }
    float4 gv = *(const float4*)&g[cc];
    float4 bev = *(const float4*)&be[cc];
    float gg[4] = {gv.x, gv.y, gv.z, gv.w};
    float eb[4] = {bev.x, bev.y, bev.z, bev.w};
#pragma unroll
    for (int a = 0; a < 4; ++a) {
      float sm = v[a][0] + v[a][1] + v[a][2] + v[a][3];
      float s2 = 0.f;
#pragma unroll
      for (int b = 0; b < 4; ++b) s2 = fmaf(v[a][b], v[a][b], s2);
#pragma unroll
      for (int m = 1; m < 32; m <<= 1) {
        sm += __shfl_xor(sm, m);
        s2 += __shfl_xor(s2, m);
      }
      const float mean = sm * (1.0f / 128.0f);
      const float var = fmaxf(s2 * (1.0f / 128.0f) - mean * mean, 0.0f);
      const float rstd = rsqrtf(var + 1e-5f);
      float4 o;
      o.x = (v[a][0] - mean) * rstd * gg[0] + eb[0];
      o.y = (v[a][1] - mean) * rstd * gg[1] + eb[1];
      o.z = (v[a][2] - mean) * rstd * gg[2] + eb[2];
      o.w = (v[a][3] - mean) * rstd * gg[3] + eb[3];
      *(float4*)&hout[(size_t)(r0 + rr + a) * Hd + cc] = o;
    }
  }
}

// ---------------- readout: softplus(silu([h,x]@Wr1+b)@Wr2+b) ----------------
__global__ __launch_bounds__(256) void k_out(const float* __restrict__ x,
    const float* __restrict__ hin, const float* __restrict__ Wr1,
    const float* __restrict__ br1, const float* __restrict__ Wr2,
    const float* __restrict__ br2, float* __restrict__ out) {
  __shared__ float rT[Hd + Fd][US];  // 192 x 36 (27 KB)
  const int t = threadIdx.x;
  const int r0 = blockIdx.x * RB;
  {
    const int r = t >> 3, s = t & 7;
    const int i = r0 + r;
    const float* hr = hin + (size_t)i * Hd + (s << 4);
#pragma unroll
    for (int u = 0; u < 4; ++u) {
      float4 v = *(const float4*)(hr + (u << 2));
      const int c = (s << 4) + (u << 2);
      rT[c + 0][r] = v.x; rT[c + 1][r] = v.y;
      rT[c + 2][r] = v.z; rT[c + 3][r] = v.w;
    }
    const float* xr = x + (size_t)i * Fd + (s << 3);
    float4 x0 = *(const float4*)(xr);
    float4 x1 = *(const float4*)(xr + 4);
    const int c = Hd + (s << 3);
    rT[c + 0][r] = x0.x; rT[c + 1][r] = x0.y;
    rT[c + 2][r] = x0.z; rT[c + 3][r] = x0.w;
    rT[c + 4][r] = x1.x; rT[c + 5][r] = x1.y;
    rT[c + 6][r] = x1.z; rT[c + 7][r] = x1.w;
  }
  __syncthreads();
  const int rg = t >> 5, cg = t & 31;
  const int rr = rg << 2, cc = cg << 2;
  float acc[4][4] = {};
#pragma unroll 4
  for (int k = 0; k < Hd + Fd; ++k) {
    float4 uv = *(const float4*)&rT[k][rr];
    float4 wv = *(const float4*)&Wr1[k * Hd + cc];
    FMA16(acc, uv, wv)
  }
  float4 b1 = *(const float4*)&br1[cc];
  float bb1[4] = {b1.x, b1.y, b1.z, b1.w};
  float4 w2 = *(const float4*)&Wr2[cc];
  float ww[4] = {w2.x, w2.y, w2.z, w2.w};
  float part[4];
#pragma unroll
  for (int a = 0; a < 4; ++a) {
    part[a] = 0.f;
#pragma unroll
    for (int b = 0; b < 4; ++b) {
      const float z = acc[a][b] + bb1[b];
      const float sil = z / (1.0f + __expf(-z));
      part[a] = fmaf(sil, ww[b], part[a]);
    }
  }
#pragma unroll
  for (int m = 1; m < 32; m <<= 1) {
#pragma unroll
    for (int a = 0; a < 4; ++a) part[a] += __shfl_xor(part[a], m);
  }
  if (cg == 0) {
    const float bias = br2[0];
#pragma unroll
    for (int a = 0; a < 4; ++a) {
      const float rv = part[a] + bias;
      out[r0 + rr + a] = fmaxf(rv, 0.0f) + log1pf(__expf(-fabsf(rv)));
    }
  }
}

extern "C" void kernel_launch(void* const* d_in, const int* in_sizes, int n_in,
                              void* d_out, int out_size, void* d_ws, size_t ws_size,
                              hipStream_t stream) {
  const float* x    = (const float*)d_in[0];
  const float* W_in = (const float*)d_in[1];
  const float* b_in = (const float*)d_in[2];
  const float* W_m1 = (const float*)d_in[3];
  const float* b_m1 = (const float*)d_in[4];
  const float* W_m2 = (const float*)d_in[5];
  const float* b_m2 = (const float*)d_in[6];
  const float* ln_g = (const float*)d_in[7];
  const float* ln_b = (const float*)d_in[8];
  const float* W_r1 = (const float*)d_in[9];
  const float* b_r1 = (const float*)d_in[10];
  const float* W_r2 = (const float*)d_in[11];
  const float* b_r2 = (const float*)d_in[12];
  float* out = (float*)d_out;

  char* ws = (char*)d_ws;
  const size_t MB = (size_t)1 << 20;
  float*          hidA = (float*)(ws);                 // 8 MB
  float*          hidB = (float*)(ws + 8 * MB);        // 8 MB (aliases part)
  ull*            part = (ull*)(ws + 8 * MB);          // 8 MB, dead before hidB use
  short*          xbhi = (short*)(ws + 16 * MB);       // 2 MB
  short*          xblo = (short*)(ws + 18 * MB);       // 2 MB
  unsigned short* nidx = (unsigned short*)(ws + 20 * MB);  // 1 MB
  float*          nw   = (float*)(ws + 21 * MB);       // 2 MB
  float*          sq   = (float*)(ws + 23 * MB);       // 64 KB

  k_input<<<dim3(Nn / 2), dim3(256), 0, stream>>>(x, W_in, b_in, hidA, sq);
  k_prep<<<dim3(Nn * 8 / 256), dim3(256), 0, stream>>>(x, xbhi, xblo);
  k_knn<<<dim3(Nn / 32 * 2), dim3(256), 0, stream>>>(xbhi, xblo, sq, part);
  k_merge<<<dim3(Nn / 4), dim3(256), 0, stream>>>(part, nidx, nw);
  k_step<<<dim3(Nn / RB), dim3(256), 0, stream>>>(x, hidA, nidx, nw, W_m1, b_m1,
                                                  W_m2, b_m2, ln_g, ln_b, hidB);
  k_step<<<dim3(Nn / RB), dim3(256), 0, stream>>>(x, hidB, nidx, nw, W_m1, b_m1,
                                                  W_m2, b_m2, ln_g, ln_b, hidA);
  k_out<<<dim3(Nn / RB), dim3(256), 0, stream>>>(x, hidA, W_r1, b_r1, W_r2, b_r2, out);
}

// Round 10
// 608.153 us; speedup vs baseline: 1.6394x; 1.2080x over previous
//
#include <hip/hip_runtime.h>
#include <math.h>

#define Nn 16384
#define Fd 64
#define Hd 128
#define Kk 32

typedef short bfrag __attribute__((ext_vector_type(8)));    // 8 bf16 = 4 VGPR
typedef float f32x16 __attribute__((ext_vector_type(16)));  // MFMA 32x32 acc
typedef unsigned long long ull;

#define FMA16(acc, qv, pv) \
  acc[0][0]=fmaf(qv.x,pv.x,acc[0][0]); acc[0][1]=fmaf(qv.x,pv.y,acc[0][1]); \
  acc[0][2]=fmaf(qv.x,pv.z,acc[0][2]); acc[0][3]=fmaf(qv.x,pv.w,acc[0][3]); \
  acc[1][0]=fmaf(qv.y,pv.x,acc[1][0]); acc[1][1]=fmaf(qv.y,pv.y,acc[1][1]); \
  acc[1][2]=fmaf(qv.y,pv.z,acc[1][2]); acc[1][3]=fmaf(qv.y,pv.w,acc[1][3]); \
  acc[2][0]=fmaf(qv.z,pv.x,acc[2][0]); acc[2][1]=fmaf(qv.z,pv.y,acc[2][1]); \
  acc[2][2]=fmaf(qv.z,pv.z,acc[2][2]); acc[2][3]=fmaf(qv.z,pv.w,acc[2][3]); \
  acc[3][0]=fmaf(qv.w,pv.x,acc[3][0]); acc[3][1]=fmaf(qv.w,pv.y,acc[3][1]); \
  acc[3][2]=fmaf(qv.w,pv.z,acc[3][2]); acc[3][3]=fmaf(qv.w,pv.w,acc[3][3]);

// ---------------- hidden0 = x @ W_in + b_in ; sq[i] = sum(x_i^2) ----------------
__global__ __launch_bounds__(256) void k_input(const float* __restrict__ x,
    const float* __restrict__ W, const float* __restrict__ b,
    float* __restrict__ hid, float* __restrict__ sq) {
  const int t = threadIdx.x;
  const int i = (blockIdx.x << 1) + (t >> 7);
  const int h = t & 127;
  const float* xr = x + (size_t)i * Fd;
  float acc = 0.f, s = 0.f;
#pragma unroll 8
  for (int f = 0; f < Fd; ++f) {
    float xv = xr[f];
    acc = fmaf(xv, W[f * Hd + h], acc);
    s = fmaf(xv, xv, s);
  }
  hid[(size_t)i * Hd + h] = acc + b[h];
  if (h == 0) sq[i] = s;
}

// ------------- precompute x as bf16 hi/lo in MFMA-fragment order -------------
__global__ __launch_bounds__(256) void k_prep(const float* __restrict__ x,
    short* __restrict__ xh, short* __restrict__ xl) {
  const int gid = blockIdx.x * 256 + threadIdx.x;
  const int p = gid >> 3, sub = gid & 7;
  const float* src = x + (size_t)p * Fd + sub * 8;
  float4 v0 = *(const float4*)src;
  float4 v1 = *(const float4*)(src + 4);
  float vv[8] = {v0.x, v0.y, v0.z, v0.w, v1.x, v1.y, v1.z, v1.w};
  bfrag hi, lo;
#pragma unroll
  for (int j = 0; j < 8; ++j) {
    unsigned u = __float_as_uint(vv[j]);
    unsigned r = u + 0x7fffu + ((u >> 16) & 1u);
    unsigned short hb = (unsigned short)(r >> 16);
    float hf = __uint_as_float((unsigned)hb << 16);
    float lof = vv[j] - hf;
    unsigned ul = __float_as_uint(lof);
    unsigned rl = ul + 0x7fffu + ((ul >> 16) & 1u);
    hi[j] = (short)hb;
    lo[j] = (short)(rl >> 16);
  }
  const size_t o = (size_t)(p >> 5) * 2048 + (size_t)sub * 256 + (size_t)(p & 31) * 8;
  *(bfrag*)(xh + o) = hi;
  *(bfrag*)(xl + o) = lo;
}

// ---------------- KNN: swapped-operand MFMA + lane-private top-32 ----------------
// Grid 512, block 256 (4 independent waves, NO barriers in main loop).
// mfma(A=points, B=queries): lane (q=lane&31, h=lane>>5) holds 16 point-dists
// of ITS query in registers. Per-lane private list of 32 u32 keys in LDS:
// key = (u18)(d2*256)<<14 | pidx  (monotone; idx tiebreak; fixed scan order
// -> fully deterministic). Insert = unrolled rescan, concurrent across lanes.
// End: one barrier + in-block bitonic merge of the 8 partials + softmax.
#define LSTR 33

__global__ __launch_bounds__(256, 2) void k_knn(const short* __restrict__ xbhi,
    const short* __restrict__ xblo, const float* __restrict__ sq,
    unsigned short* __restrict__ nidx, float* __restrict__ nw) {
  __shared__ unsigned tk[256 * LSTR];   // 256 lane-private lists (33.8 KB)
  __shared__ unsigned scr[256 * 17];    // slot staging / merge scratch (17.4 KB)

  const int t = threadIdx.x;
  const int w = t >> 6;
  const int lane = t & 63;
  const int h = lane >> 5;
  const int q = lane & 31;
  const int qg0 = (int)blockIdx.x * 32;
  const int selfq = qg0 + q;
  const float sqq = sq[selfq];

  const char* xh = (const char*)xbhi;
  const char* xl = (const char*)xblo;

  // query fragments (B operand), resident: 32 VGPR
  bfrag qhi[4], qlo[4];
  {
    const size_t a0 = (size_t)blockIdx.x * 4096 + (size_t)lane * 16;
#pragma unroll
    for (int s = 0; s < 4; ++s) {
      qhi[s] = *(const bfrag*)(xh + a0 + s * 1024);
      qlo[s] = *(const bfrag*)(xl + a0 + s * 1024);
    }
  }
  asm volatile("" :: "v"(qhi[0]), "v"(qhi[1]), "v"(qhi[2]), "v"(qhi[3]),
                     "v"(qlo[0]), "v"(qlo[1]), "v"(qlo[2]), "v"(qlo[3]));

  unsigned* mylist = &tk[(w * 64 + lane) * LSTR];
  unsigned* myscr = &scr[t * 17];
  unsigned thr = 0xFFFFFFFFu;
  int cnt = 0;

  // point-group g = tile*4 + w ; lane's rows = r + (r&~3) + 4h
#define LOADP(TL, PH, PL) { \
  const size_t bb_ = (size_t)((TL) * 4 + w) * 4096 + (size_t)lane * 16; \
  _Pragma("unroll") for (int s_ = 0; s_ < 4; ++s_) { \
    PH[s_] = *(const bfrag*)(xh + bb_ + s_ * 1024); \
    PL[s_] = *(const bfrag*)(xl + bb_ + s_ * 1024); } }

#define SPLOAD(TL, SP) { \
  const int p0_ = (TL) * 128 + w * 32 + 4 * h; \
  _Pragma("unroll") for (int r_ = 0; r_ < 16; ++r_) \
    SP[r_] = sq[p0_ + r_ + (r_ & ~3)]; }

#define PIN(PH, PL) asm volatile("" :: "v"(PH[0]), "v"(PH[1]), "v"(PH[2]), "v"(PH[3]), \
                                       "v"(PL[0]), "v"(PL[1]), "v"(PL[2]), "v"(PL[3]));

#define MFMA12(A0, PH, PL) { \
  _Pragma("unroll") for (int s_ = 0; s_ < 4; ++s_) \
    A0 = __builtin_amdgcn_mfma_f32_32x32x16_bf16(PH[s_], qhi[s_], A0, 0, 0, 0); \
  _Pragma("unroll") for (int s_ = 0; s_ < 4; ++s_) \
    A0 = __builtin_amdgcn_mfma_f32_32x32x16_bf16(PH[s_], qlo[s_], A0, 0, 0, 0); \
  _Pragma("unroll") for (int s_ = 0; s_ < 4; ++s_) \
    A0 = __builtin_amdgcn_mfma_f32_32x32x16_bf16(PL[s_], qhi[s_], A0, 0, 0, 0); }

#define RESCAN(MX, MP) { \
  MX = 0u; MP = 0; \
  _Pragma("unroll") for (int e_ = 0; e_ < 32; ++e_) { \
    const unsigned v_ = mylist[e_]; \
    if (v_ > MX) { MX = v_; MP = e_; } } }

#define STEP(TL, PHc, PLc, SPc, PHn, PLn, SPn) { \
  const int tl_ = (TL); \
  if (tl_ + 1 < 128) { LOADP(tl_ + 1, PHn, PLn) SPLOAD(tl_ + 1, SPn) } \
  f32x16 a0_; \
  _Pragma("unroll") for (int i_ = 0; i_ < 16; ++i_) a0_[i_] = 0.f; \
  MFMA12(a0_, PHc, PLc) \
  PIN(PHn, PLn) \
  unsigned mask_ = 0u; \
  const int pb_ = tl_ * 128 + w * 32 + 4 * h; \
  _Pragma("unroll") for (int r_ = 0; r_ < 16; ++r_) { \
    const int pidx_ = pb_ + r_ + (r_ & ~3); \
    float d2_ = fmaf(-2.0f, a0_[r_], SPc[r_]) + sqq; \
    d2_ = fmaxf(d2_, 0.0f); \
    unsigned dq_ = (unsigned)(d2_ * 256.0f); \
    dq_ = dq_ > 0x3FFEFu ? 0x3FFEFu : dq_; \
    unsigned key_ = (dq_ << 14) | (unsigned)pidx_; \
    if (pidx_ == selfq) key_ = 0xFFFFFFFFu; \
    myscr[r_] = key_; \
    if (key_ < thr) mask_ |= (1u << r_); \
  } \
  while (__any(mask_ != 0u)) { \
    if (mask_) { \
      const int r_ = __builtin_ctz(mask_); \
      mask_ &= mask_ - 1u; \
      const unsigned k_ = myscr[r_]; \
      if (cnt < 32) { \
        mylist[cnt] = k_; \
        cnt++; \
        if (cnt == 32) { unsigned mx_; int mp_; RESCAN(mx_, mp_) thr = mx_; } \
      } else if (k_ < thr) { \
        unsigned mx_; int mp_; RESCAN(mx_, mp_) \
        if (k_ < mx_) mylist[mp_] = k_; \
        thr = mx_; \
      } \
    } \
  } }

  bfrag phA[4], plA[4], phB[4], plB[4];
  float spA[16], spB[16];
  LOADP(0, phA, plA)
  SPLOAD(0, spA)
  PIN(phA, plA)
  for (int tl = 0; tl < 126; tl += 2) {
    STEP(tl, phA, plA, spA, phB, plB, spB)
    STEP(tl + 1, phB, plB, spB, phA, plA, spA)
  }
  STEP(126, phA, plA, spA, phB, plB, spB)
  STEP(127, phB, plB, spB, phA, plA, spA)

  __syncthreads();

  // ---- in-block merge: 8 partials -> top-32 + softmax. Wave w: queries w*8.. ----
#define SORT64(V) { \
  _Pragma("unroll") for (int k_ = 2; k_ <= 64; k_ <<= 1) { \
    _Pragma("unroll") for (int j_ = k_ >> 1; j_ >= 1; j_ >>= 1) { \
      const unsigned o_ = (unsigned)__shfl_xor((int)V, j_); \
      const bool km_ = ((lane & j_) == 0) == ((lane & k_) == 0); \
      V = km_ ? (V < o_ ? V : o_) : (V > o_ ? V : o_); \
    } } }

#define MERGE6(V) { \
  _Pragma("unroll") for (int j_ = 32; j_ >= 1; j_ >>= 1) { \
    const unsigned o_ = (unsigned)__shfl_xor((int)V, j_); \
    const bool km_ = ((lane & j_) == 0); \
    V = km_ ? (V < o_ ? V : o_) : (V > o_ ? V : o_); \
  } }

  unsigned* S = &scr[w * 128];
  for (int s8 = 0; s8 < 8; ++s8) {
    const int qq = w * 8 + s8;
    // phase A: per source-wave w2, sort its (h0,h1) 64 keys; keep low 32
#pragma unroll
    for (int w2 = 0; w2 < 4; ++w2) {
      unsigned v = tk[(w2 * 64 + (lane & 32) + qq) * LSTR + (lane & 31)];
      SORT64(v)
      if (lane < 32) S[w2 * 32 + lane] = v;
    }
    // phase B: pairwise bitonic merges
    {
      unsigned v = (lane < 32) ? S[0 * 32 + lane] : S[1 * 32 + (63 - lane)];
      MERGE6(v)
      if (lane < 32) S[0 * 32 + lane] = v;
    }
    {
      unsigned v = (lane < 32) ? S[2 * 32 + lane] : S[3 * 32 + (63 - lane)];
      MERGE6(v)
      if (lane < 32) S[2 * 32 + lane] = v;
    }
    {
      unsigned v = (lane < 32) ? S[0 * 32 + lane] : S[2 * 32 + (63 - lane)];
      MERGE6(v)
      // lanes 0..31: final top-32 ascending
      const float d2 = (float)(v >> 14) * (1.0f / 256.0f);
      const float d = sqrtf(d2);
      const float dmin = __shfl(d, 0);
      float e = (lane < 32) ? __expf((dmin - d) * 2.0f) : 0.f;
      float s2 = e;
#pragma unroll
      for (int m = 1; m < 64; m <<= 1) s2 += __shfl_xor(s2, m);
      if (lane < 32) {
        nw[(size_t)(qg0 + qq) * Kk + lane] = e / s2;
        nidx[(size_t)(qg0 + qq) * Kk + lane] = (unsigned short)(v & 0x3FFFu);
      }
    }
  }
#undef LOADP
#undef SPLOAD
#undef PIN
#undef MFMA12
#undef RESCAN
#undef STEP
#undef SORT64
#undef MERGE6
}

// ---------------- one message-pass step, fused: gather+MLP+LN ----------------
#define RB 32
#define US 36

__global__ __launch_bounds__(256) void k_step(const float* __restrict__ x,
    const float* __restrict__ hin, const unsigned short* __restrict__ nidx,
    const float* __restrict__ nw, const float* __restrict__ Wm1,
    const float* __restrict__ bm1, const float* __restrict__ Wm2,
    const float* __restrict__ bm2, const float* __restrict__ g,
    const float* __restrict__ be, float* __restrict__ hout) {
  __shared__ float updT[2 * Hd + Fd][US];  // upd_in transposed: 320 x 36 (46 KB)
  __shared__ float t1T[Hd][US];            // silu(GEMM1) transposed (18 KB)
  const int t = threadIdx.x;
  const int r0 = blockIdx.x * RB;

  { // stage: hidden | agg (gather) | x, all transposed
    const int r = t >> 3, s = t & 7;
    const int i = r0 + r;
    const float* hr = hin + (size_t)i * Hd + (s << 4);
#pragma unroll
    for (int u = 0; u < 4; ++u) {
      float4 v = *(const float4*)(hr + (u << 2));
      const int c = (s << 4) + (u << 2);
      updT[c + 0][r] = v.x; updT[c + 1][r] = v.y;
      updT[c + 2][r] = v.z; updT[c + 3][r] = v.w;
    }
    float a[16];
#pragma unroll
    for (int u = 0; u < 16; ++u) a[u] = 0.f;
    const unsigned short* ir = nidx + i * Kk;
    const float* wr = nw + i * Kk;
    for (int k = 0; k < Kk; ++k) {
      const float wk = wr[k];
      const float* hv = hin + (size_t)ir[k] * Hd + (s << 4);
#pragma unroll
      for (int u = 0; u < 4; ++u) {
        float4 v = *(const float4*)(hv + (u << 2));
        a[(u << 2) + 0] = fmaf(wk, v.x, a[(u << 2) + 0]);
        a[(u << 2) + 1] = fmaf(wk, v.y, a[(u << 2) + 1]);
        a[(u << 2) + 2] = fmaf(wk, v.z, a[(u << 2) + 2]);
        a[(u << 2) + 3] = fmaf(wk, v.w, a[(u << 2) + 3]);
      }
    }
#pragma unroll
    for (int u = 0; u < 16; ++u) updT[Hd + (s << 4) + u][r] = a[u];
    const float* xr = x + (size_t)i * Fd + (s << 3);
    float4 x0 = *(const float4*)(xr);
    float4 x1 = *(const float4*)(xr + 4);
    const int c = 2 * Hd + (s << 3);
    updT[c + 0][r] = x0.x; updT[c + 1][r] = x0.y;
    updT[c + 2][r] = x0.z; updT[c + 3][r] = x0.w;
    updT[c + 4][r] = x1.x; updT[c + 5][r] = x1.y;
    updT[c + 6][r] = x1.z; updT[c + 7][r] = x1.w;
  }
  __syncthreads();

  const int rg = t >> 5, cg = t & 31;
  const int rr = rg << 2, cc = cg << 2;
  { // GEMM1 [32x320]x[320x128] + silu -> t1T
    float acc[4][4] = {};
#pragma unroll 4
    for (int k = 0; k < 2 * Hd + Fd; ++k) {
      float4 uv = *(const float4*)&updT[k][rr];
      float4 wv = *(const float4*)&Wm1[k * Hd + cc];
      FMA16(acc, uv, wv)
    }
    float4 b1 = *(const float4*)&bm1[cc];
    float bb1[4] = {b1.x, b1.y, b1.z, b1.w};
#pragma unroll
    for (int a = 0; a < 4; ++a)
#pragma unroll
      for (int b = 0; b < 4; ++b) {
        const float z = acc[a][b] + bb1[b];
        t1T[cc + b][rr + a] = z / (1.0f + __expf(-z));
      }
  }
  __syncthreads();
  { // GEMM2 [32x128]x[128x128] + residual + LayerNorm
    float acc[4][4] = {};
#pragma unroll 4
    for (int k = 0; k < Hd; ++k) {
      float4 uv = *(const float4*)&t1T[k][rr];
      float4 wv = *(const float4*)&Wm2[k * Hd + cc];
      FMA16(acc, uv, wv)
    }
    float4 b2 = *(const float4*)&bm2[cc];
    float bb2[4] = {b2.x, b2.y, b2.z, b2.w};
    float v[4][4];
#pragma unroll
    for (int b = 0; b < 4; ++b) {
      float4 hres = *(const float4*)&updT[cc + b][rr];  // residual = staged hidden
      v[0][b] = hres.x + acc[0][b] + bb2[b];
      v[1][b] = hres.y + acc[1][b] + bb2[b];
      v[2][b] = hres.z + acc[2][b] + bb2[b];
      v[3][b] = hres.w + acc[3][b] + bb2[b];
    }
    float4 gv = *(const float4*)&g[cc];
    float4 bev = *(const float4*)&be[cc];
    float gg[4] = {gv.x, gv.y, gv.z, gv.w};
    float eb[4] = {bev.x, bev.y, bev.z, bev.w};
#pragma unroll
    for (int a = 0; a < 4; ++a) {
      float sm = v[a][0] + v[a][1] + v[a][2] + v[a][3];
      float s2 = 0.f;
#pragma unroll
      for (int b = 0; b < 4; ++b) s2 = fmaf(v[a][b], v[a][b], s2);
#pragma unroll
      for (int m = 1; m < 32; m <<= 1) {
        sm += __shfl_xor(sm, m);
        s2 += __shfl_xor(s2, m);
      }
      const float mean = sm * (1.0f / 128.0f);
      const float var = fmaxf(s2 * (1.0f / 128.0f) - mean * mean, 0.0f);
      const float rstd = rsqrtf(var + 1e-5f);
      float4 o;
      o.x = (v[a][0] - mean) * rstd * gg[0] + eb[0];
      o.y = (v[a][1] - mean) * rstd * gg[1] + eb[1];
      o.z = (v[a][2] - mean) * rstd * gg[2] + eb[2];
      o.w = (v[a][3] - mean) * rstd * gg[3] + eb[3];
      *(float4*)&hout[(size_t)(r0 + rr + a) * Hd + cc] = o;
    }
  }
}

// ---------------- readout: softplus(silu([h,x]@Wr1+b)@Wr2+b) ----------------
__global__ __launch_bounds__(256) void k_out(const float* __restrict__ x,
    const float* __restrict__ hin, const float* __restrict__ Wr1,
    const float* __restrict__ br1, const float* __restrict__ Wr2,
    const float* __restrict__ br2, float* __restrict__ out) {
  __shared__ float rT[Hd + Fd][US];  // 192 x 36 (27 KB)
  const int t = threadIdx.x;
  const int r0 = blockIdx.x * RB;
  {
    const int r = t >> 3, s = t & 7;
    const int i = r0 + r;
    const float* hr = hin + (size_t)i * Hd + (s << 4);
#pragma unroll
    for (int u = 0; u < 4; ++u) {
      float4 v = *(const float4*)(hr + (u << 2));
      const int c = (s << 4) + (u << 2);
      rT[c + 0][r] = v.x; rT[c + 1][r] = v.y;
      rT[c + 2][r] = v.z; rT[c + 3][r] = v.w;
    }
    const float* xr = x + (size_t)i * Fd + (s << 3);
    float4 x0 = *(const float4*)(xr);
    float4 x1 = *(const float4*)(xr + 4);
    const int c = Hd + (s << 3);
    rT[c + 0][r] = x0.x; rT[c + 1][r] = x0.y;
    rT[c + 2][r] = x0.z; rT[c + 3][r] = x0.w;
    rT[c + 4][r] = x1.x; rT[c + 5][r] = x1.y;
    rT[c + 6][r] = x1.z; rT[c + 7][r] = x1.w;
  }
  __syncthreads();
  const int rg = t >> 5, cg = t & 31;
  const int rr = rg << 2, cc = cg << 2;
  float acc[4][4] = {};
#pragma unroll 4
  for (int k = 0; k < Hd + Fd; ++k) {
    float4 uv = *(const float4*)&rT[k][rr];
    float4 wv = *(const float4*)&Wr1[k * Hd + cc];
    FMA16(acc, uv, wv)
  }
  float4 b1 = *(const float4*)&br1[cc];
  float bb1[4] = {b1.x, b1.y, b1.z, b1.w};
  float4 w2 = *(const float4*)&Wr2[cc];
  float ww[4] = {w2.x, w2.y, w2.z, w2.w};
  float part[4];
#pragma unroll
  for (int a = 0; a < 4; ++a) {
    part[a] = 0.f;
#pragma unroll
    for (int b = 0; b < 4; ++b) {
      const float z = acc[a][b] + bb1[b];
      const float sil = z / (1.0f + __expf(-z));
      part[a] = fmaf(sil, ww[b], part[a]);
    }
  }
#pragma unroll
  for (int m = 1; m < 32; m <<= 1) {
#pragma unroll
    for (int a = 0; a < 4; ++a) part[a] += __shfl_xor(part[a], m);
  }
  if (cg == 0) {
    const float bias = br2[0];
#pragma unroll
    for (int a = 0; a < 4; ++a) {
      const float rv = part[a] + bias;
      out[r0 + rr + a] = fmaxf(rv, 0.0f) + log1pf(__expf(-fabsf(rv)));
    }
  }
}

extern "C" void kernel_launch(void* const* d_in, const int* in_sizes, int n_in,
                              void* d_out, int out_size, void* d_ws, size_t ws_size,
                              hipStream_t stream) {
  const float* x    = (const float*)d_in[0];
  const float* W_in = (const float*)d_in[1];
  const float* b_in = (const float*)d_in[2];
  const float* W_m1 = (const float*)d_in[3];
  const float* b_m1 = (const float*)d_in[4];
  const float* W_m2 = (const float*)d_in[5];
  const float* b_m2 = (const float*)d_in[6];
  const float* ln_g = (const float*)d_in[7];
  const float* ln_b = (const float*)d_in[8];
  const float* W_r1 = (const float*)d_in[9];
  const float* b_r1 = (const float*)d_in[10];
  const float* W_r2 = (const float*)d_in[11];
  const float* b_r2 = (const float*)d_in[12];
  float* out = (float*)d_out;

  char* ws = (char*)d_ws;
  const size_t MB = (size_t)1 << 20;
  float*          hidA = (float*)(ws);                 // 8 MB
  float*          hidB = (float*)(ws + 8 * MB);        // 8 MB
  short*          xbhi = (short*)(ws + 16 * MB);       // 2 MB
  short*          xblo = (short*)(ws + 18 * MB);       // 2 MB
  unsigned short* nidx = (unsigned short*)(ws + 20 * MB);  // 1 MB
  float*          nw   = (float*)(ws + 21 * MB);       // 2 MB
  float*          sq   = (float*)(ws + 23 * MB);       // 64 KB

  k_input<<<dim3(Nn / 2), dim3(256), 0, stream>>>(x, W_in, b_in, hidA, sq);
  k_prep<<<dim3(Nn * 8 / 256), dim3(256), 0, stream>>>(x, xbhi, xblo);
  k_knn<<<dim3(Nn / 32), dim3(256), 0, stream>>>(xbhi, xblo, sq, nidx, nw);
  k_step<<<dim3(Nn / RB), dim3(256), 0, stream>>>(x, hidA, nidx, nw, W_m1, b_m1,
                                                  W_m2, b_m2, ln_g, ln_b, hidB);
  k_step<<<dim3(Nn / RB), dim3(256), 0, stream>>>(x, hidB, nidx, nw, W_m1, b_m1,
                                                  W_m2, b_m2, ln_g, ln_b, hidA);
  k_out<<<dim3(Nn / RB), dim3(256), 0, stream>>>(x, hidA, W_r1, b_r1, W_r2, b_r2, out);
}